// Round 17
// baseline (270.644 us; speedup 1.0000x reference)
//
#include <hip/hip_runtime.h>
#include <math.h>

typedef __attribute__((ext_vector_type(8))) short s16x8;
typedef __attribute__((ext_vector_type(4))) short s16x4;
typedef __attribute__((ext_vector_type(4))) float f32x4;

__device__ __forceinline__ float b2f(unsigned short u) {
    union { unsigned u; float f; } x;
    x.u = ((unsigned)u) << 16;
    return x.f;
}
__device__ __forceinline__ unsigned short f2b(float f) {
    union { float f; unsigned u; } x;
    x.f = f;
    unsigned u = x.u;
    return (unsigned short)((u + 0x7FFFu + ((u >> 16) & 1u)) >> 16);
}
__device__ __forceinline__ f32x4 mfma16(s16x8 a, s16x8 b, f32x4 c) {
    return __builtin_amdgcn_mfma_f32_16x16x32_bf16(a, b, c, 0, 0, 0);
}
__device__ __forceinline__ float gelu_exact(float x) {
    return 0.5f * x * (1.0f + erff(x * 0.70710678118654752440f));
}
__device__ __forceinline__ void gload_lds16(const void* g, void* l) {
    __builtin_amdgcn_global_load_lds(
        (const __attribute__((address_space(1))) unsigned int*)g,
        (__attribute__((address_space(3))) unsigned int*)l, 16, 0, 0);
}
// raster voxel of (block, position) for split s=1<<logs, bsz=1<<lbsz
__device__ __forceinline__ int voxof(int blk, int pos, int logs, int lbsz) {
    int bm = (1 << lbsz) - 1, sm = (1 << logs) - 1;
    int ix = pos & bm, iy = (pos >> lbsz) & bm, iz = pos >> (2 * lbsz);
    int gx = blk & sm, gy = (blk >> logs) & sm, gz = blk >> (2 * logs);
    return (((gz << lbsz) + iz) << 8) + (((gy << lbsz) + iy) << 4) + ((gx << lbsz) + ix);
}
__device__ __forceinline__ int blkof(int v, int logs, int lbsz) {
    int gx = (v & 15) >> lbsz, gy = ((v >> 4) & 15) >> lbsz, gz = ((v >> 8) & 15) >> lbsz;
    return (((gz << logs) + gy) << logs) + gx;
}

// ---------------------------------------------------------------------------
// Prologue: weights->bf16 (bx<3328), x transpose (bx<4352), Rb zero (rest)
// ---------------------------------------------------------------------------
__global__ __launch_bounds__(256) void prologue_k(
    const float* w0, const float* w1, const float* w2, const float* w3,
    const float* w4, const float* w5, const float* w6,
    unsigned short* __restrict__ wdst, const float* __restrict__ x,
    float* __restrict__ Xt, unsigned short* __restrict__ Xtb,
    float* __restrict__ Rb) {
    __shared__ float tile[32][33];
    int bx = blockIdx.x;
    if (bx < 3328) {
        int i = (bx * 256 + threadIdx.x) * 4;
        const float* s; int off;
        if (i < 786432)        { s = w0; off = 0; }
        else if (i < 1048576)  { s = w1; off = 786432; }
        else if (i < 1835008)  { s = w2; off = 1048576; }
        else if (i < 2097152)  { s = w3; off = 1835008; }
        else if (i < 2621440)  { s = w4; off = 2097152; }
        else if (i < 3145728)  { s = w5; off = 2621440; }
        else                   { s = w6; off = 3145728; }
        float4 v = *reinterpret_cast<const float4*>(s + (i - off));
        wdst[i + 0] = f2b(v.x); wdst[i + 1] = f2b(v.y);
        wdst[i + 2] = f2b(v.z); wdst[i + 3] = f2b(v.w);
    } else if (bx < 4352) {
        int t = bx - 3328;
        int v0 = (t & 127) * 32, c0 = (t >> 7) * 32;
        int tx = threadIdx.x & 31, ty = threadIdx.x >> 5;
#pragma unroll
        for (int j = 0; j < 32; j += 8)
            tile[ty + j][tx] = x[(size_t)(c0 + ty + j) * 4096 + v0 + tx];
        __syncthreads();
#pragma unroll
        for (int j = 0; j < 32; j += 8) {
            float v = tile[tx][ty + j];
            size_t o = (size_t)(v0 + ty + j) * 256 + c0 + tx;
            Xt[o] = v;
            Xtb[o] = f2b(v);
        }
    } else {
        int idx = ((bx - 4352) * 256 + threadIdx.x) * 4;
        if (idx < 149760) {
            float4 z4 = make_float4(0.f, 0.f, 0.f, 0.f);
            *reinterpret_cast<float4*>(Rb + idx) = z4;
        }
    }
}

// ---------------------------------------------------------------------------
// bf16 MFMA GEMM, BM=32*MFR, BN=64, BK=64, 256 thr (4 waves 2x2), z-batched.
// AF32: 0 = A bf16 gload_lds; 1 = A f32 reg-staged;
//       2 = A f32 + RLN[blk] (ZS=1); 3 = A bf16 + RLN[blk] (ZS=1)
// EPI:  1 = FFN2: v += bf16 T[z] + RLN[goff+blk] + X; write bf16
// VT:   n in [512,768) also to vt[z*zsV + (n-512)*mtot + m]
// ZS:   1 = per-split mode (logs=z); 2 = inter mode (M={1,8,64,512}[z], goff rows)
// QSC:  1 = scale Q columns (n<256) by cscale = log2(e)/sqrt(32)
// ---------------------------------------------------------------------------
template <int MFR, int HASB, int ACT, int OBF, int VT, int AF32, int EPI, int ZS, int QSC>
__global__ __launch_bounds__(256) void gemm_k(
    const void* __restrict__ Aptr, const unsigned short* __restrict__ W,
    const float* __restrict__ bias, void* __restrict__ outp,
    int M, int N, int K, int ldC,
    long zsA, long zsW, long zsB, long zsC,
    unsigned short* __restrict__ vt, int mtot, long zsV,
    const void* __restrict__ Tresv, const float* __restrict__ RLNres,
    const float* __restrict__ Xres) {
    constexpr int BM = 32 * MFR;
    __shared__ unsigned short As[BM * 64];
    __shared__ unsigned short Ws[64 * 64];
    const int z = blockIdx.z;
    const int logs = (ZS == 1) ? z : 0;
    const int lbsz = (ZS == 1) ? (4 - z) : 4;
    const int goffc[4] = {0, 1, 9, 73};
    const int Mzc[4] = {1, 8, 64, 512};
    const int Me = (ZS == 2) ? Mzc[z] : M;
    const int m0 = blockIdx.y * BM, n0 = blockIdx.x * 64;
    if (ZS == 2 && m0 >= Me) return;
    const unsigned short* Ab = (const unsigned short*)Aptr +
        ((AF32 == 0 || AF32 == 3) ? ((size_t)z * zsA + (ZS == 2 ? (size_t)goffc[z] * K : 0)) : 0);
    const float* Af = (const float*)Aptr +
        ((AF32 == 1 || AF32 == 2) ? ((size_t)z * zsA + (ZS == 2 ? (size_t)goffc[z] * K : 0)) : 0);
    W += (size_t)z * zsW;
    const float* biasz = bias + (HASB ? (size_t)z * zsB : 0);
    char* outc = (char*)outp +
        ((size_t)z * zsC + (ZS == 2 ? (size_t)goffc[z] * ldC : 0)) * ((OBF || EPI) ? 2 : 4);
    const float* RLNz = RLNres + (ZS == 1 ? goffc[z] * 256 : 0);
    const unsigned short* Tzb = (const unsigned short*)Tresv + (ZS == 1 ? (size_t)z * 1048576 : 0);

    const int tid = threadIdx.x;
    const int wave = tid >> 6, lane = tid & 63;
    const int l15 = lane & 15, l4 = lane >> 4;
    const int wr = wave >> 1, wc = wave & 1;
    const int srow = lane >> 3;
    const int schunk = (lane & 7) ^ srow;
    f32x4 acc[MFR][2] = {};
    for (int k0 = 0; k0 < K; k0 += 64) {
        s16x8 sreg[MFR];
        if (AF32) {
#pragma unroll
            for (int i = 0; i < MFR; ++i) {
                int ca = wave * MFR + i;
                int gr = m0 + ca * 8 + srow;
                gr = gr < Me ? gr : (Me - 1);
                s16x8 pk;
                if (AF32 == 3) {
                    s16x8 tb = *reinterpret_cast<const s16x8*>(Ab + (size_t)gr * K + k0 + schunk * 8);
                    const float* rl = RLNz + (size_t)blkof(gr, logs, lbsz) * 256 + k0 + schunk * 8;
#pragma unroll
                    for (int e = 0; e < 8; ++e) pk[e] = (short)f2b(b2f((unsigned short)tb[e]) + rl[e]);
                } else {
                    const float* src = Af + (size_t)gr * K + k0 + schunk * 8;
                    float4 u = *reinterpret_cast<const float4*>(src);
                    float4 w2 = *reinterpret_cast<const float4*>(src + 4);
                    if (AF32 == 2) {
                        const float* rl = RLNz + (size_t)blkof(gr, logs, lbsz) * 256 + k0 + schunk * 8;
                        float4 a = *reinterpret_cast<const float4*>(rl);
                        float4 b = *reinterpret_cast<const float4*>(rl + 4);
                        u.x += a.x; u.y += a.y; u.z += a.z; u.w += a.w;
                        w2.x += b.x; w2.y += b.y; w2.z += b.z; w2.w += b.w;
                    }
                    pk[0] = (short)f2b(u.x); pk[1] = (short)f2b(u.y);
                    pk[2] = (short)f2b(u.z); pk[3] = (short)f2b(u.w);
                    pk[4] = (short)f2b(w2.x); pk[5] = (short)f2b(w2.y);
                    pk[6] = (short)f2b(w2.z); pk[7] = (short)f2b(w2.w);
                }
                sreg[i] = pk;
            }
        }
        __syncthreads();
        if (AF32) {
#pragma unroll
            for (int i = 0; i < MFR; ++i) {
                int ca = wave * MFR + i;
                *reinterpret_cast<s16x8*>((char*)As + ca * 1024 + lane * 16) = sreg[i];
            }
        } else {
#pragma unroll
            for (int i = 0; i < MFR; ++i) {
                int ca = wave * MFR + i;
                int gr = m0 + ca * 8 + srow;
                gr = gr < Me ? gr : (Me - 1);
                gload_lds16(Ab + (size_t)gr * K + k0 + schunk * 8, (char*)As + ca * 1024);
            }
        }
#pragma unroll
        for (int i = 0; i < 2; ++i) {
            int cb = wave * 2 + i;
            int gr = n0 + cb * 8 + srow;
            gload_lds16(W + (size_t)gr * K + k0 + schunk * 8, (char*)Ws + cb * 1024);
        }
        asm volatile("s_waitcnt vmcnt(0)" ::: "memory");
        __syncthreads();
#pragma unroll
        for (int ks = 0; ks < 2; ++ks) {
            s16x8 af[MFR], bf[2];
#pragma unroll
            for (int mf = 0; mf < MFR; ++mf) {
                int row = wr * (MFR * 16) + mf * 16 + l15;
                int ch = (ks * 4 + l4) ^ (row & 7);
                af[mf] = *reinterpret_cast<const s16x8*>((char*)As + row * 128 + ch * 16);
            }
#pragma unroll
            for (int nf = 0; nf < 2; ++nf) {
                int row = wc * 32 + nf * 16 + l15;
                int ch = (ks * 4 + l4) ^ (row & 7);
                bf[nf] = *reinterpret_cast<const s16x8*>((char*)Ws + row * 128 + ch * 16);
            }
#pragma unroll
            for (int mf = 0; mf < MFR; ++mf)
#pragma unroll
                for (int nf = 0; nf < 2; ++nf)
                    acc[mf][nf] = mfma16(af[mf], bf[nf], acc[mf][nf]);
        }
    }
#pragma unroll
    for (int nf = 0; nf < 2; ++nf) {
        int n = n0 + wc * 32 + nf * 16 + l15;
        float bv = HASB ? biasz[n] : 0.0f;
#pragma unroll
        for (int mf = 0; mf < MFR; ++mf) {
            float vr[4];
#pragma unroll
            for (int r = 0; r < 4; ++r) {
                int m = m0 + wr * (MFR * 16) + mf * 16 + l4 * 4 + r;
                float v = acc[mf][nf][r] + bv;
                if (ACT == 1) v = gelu_exact(v);
                if (QSC) { if (n < 256) v *= (0.17677669529663687f * 1.44269504088896f); }
                vr[r] = v;
                if (m < Me) {
                    size_t co = (size_t)m * ldC + n;
                    if (EPI == 1) {
                        v += b2f(Tzb[(size_t)m * 256 + n]) +
                             RLNz[(size_t)blkof(m, logs, lbsz) * 256 + n] +
                             Xres[(size_t)m * 256 + n];
                        ((unsigned short*)outc)[co] = f2b(v);
                    } else if (OBF) {
                        ((unsigned short*)outc)[co] = f2b(v);
                    } else {
                        ((float*)outc)[co] = v;
                    }
                }
            }
            if (VT) {
                if ((ZS != 2 || z == 3) && n >= 512) {
                    s16x4 pk;
#pragma unroll
                    for (int r = 0; r < 4; ++r) pk[r] = (short)f2b(vr[r]);
                    int mb = m0 + wr * (MFR * 16) + mf * 16 + l4 * 4;
                    *reinterpret_cast<s16x4*>(vt + (size_t)z * zsV + (size_t)(n - 512) * mtot + mb) = pk;
                }
            }
        }
    }
}

// ---------------------------------------------------------------------------
// Shared MFMA flash-attention tile body (fixed-m softmax, Q pre-scaled so
// P = exp2(S) directly). VST=0: V^T via gload_lds16 (needs 8 consecutive
// positions == 8 consecutive voxels). VST=1: reg-staged 2x4-voxel loads
// (required for lbsz==2, z=2 intra).
// ---------------------------------------------------------------------------
template <int VST>
__device__ __forceinline__ void attn_core(
    const unsigned short* QKV, const unsigned short* Vtg,
    unsigned short* Opart, float* ML,
    int L, int Mtok, int logs, int lbsz,
    int blk, int h, int KS, int ks, int q0,
    unsigned short* Kl, unsigned short* Vl, unsigned short* Pl) {
    const int wave = threadIdx.x >> 6, lane = threadIdx.x & 63;
    const int l15 = lane & 15, l4 = lane >> 4;
    char* Plw = (char*)Pl + wave * 2048;

    const int qvox = voxof(blk, q0 + l15, logs, lbsz);
    s16x8 qf = *reinterpret_cast<const s16x8*>(QKV + (size_t)qvox * 768 + h * 32 + l4 * 8);

    f32x4 o0 = {}, o1 = {};
    float lR = 0.f;

    const int krow = threadIdx.x >> 2, kch = threadIdx.x & 3;
    const int kcol = (kch ^ (krow & 3)) * 8;
    const int vd = threadIdx.x >> 3, vc = threadIdx.x & 7;
    const int vrun = (vc ^ (vd & 7)) * 8;

    const int nt = L / (64 * KS);
    const int kb0 = ks * (L / KS);
    const int vstep = (nt > 1)
        ? (voxof(blk, kb0 + 64, logs, lbsz) - voxof(blk, kb0, logs, lbsz)) : 0;
    const unsigned short* ksrc =
        QKV + (size_t)voxof(blk, kb0 + krow, logs, lbsz) * 768 + 256 + h * 32 + kcol;
    const unsigned short* vsrc =
        Vtg + (size_t)(h * 32 + vd) * Mtok + voxof(blk, kb0 + vrun, logs, lbsz);
    const unsigned short* vsrc2 =
        Vtg + (size_t)(h * 32 + vd) * Mtok + voxof(blk, kb0 + vrun + 4, logs, lbsz);
    const size_t kadv = (size_t)vstep * 768;
    char* kdst = (char*)Kl + wave * 1024;
    char* vdst = (char*)Vl + wave * 1024;

    for (int it = 0; it < nt; ++it) {
        __syncthreads();
        gload_lds16(ksrc, kdst);
        if (VST == 0) {
            gload_lds16(vsrc, vdst);
        } else {
            s16x4 lo = *reinterpret_cast<const s16x4*>(vsrc);
            s16x4 hi = *reinterpret_cast<const s16x4*>(vsrc2);
            s16x8 vv;
            vv[0] = lo[0]; vv[1] = lo[1]; vv[2] = lo[2]; vv[3] = lo[3];
            vv[4] = hi[0]; vv[5] = hi[1]; vv[6] = hi[2]; vv[7] = hi[3];
            *reinterpret_cast<s16x8*>((char*)Vl + threadIdx.x * 16) = vv;
        }
        ksrc += kadv; vsrc += vstep; vsrc2 += vstep;
        asm volatile("s_waitcnt vmcnt(0)" ::: "memory");
        __syncthreads();

        f32x4 st[4];
        const f32x4 zz = {0.f, 0.f, 0.f, 0.f};
#pragma unroll
        for (int t4 = 0; t4 < 4; ++t4) {
            s16x8 kf = *reinterpret_cast<const s16x8*>(
                (char*)Kl + (t4 * 16 + l15) * 64 + ((l4 ^ (l15 & 3)) << 4));
            st[t4] = mfma16(kf, qf, zz);
        }
        float rsum = 0.f;
#pragma unroll
        for (int t4 = 0; t4 < 4; ++t4) {
            float p0 = exp2f(st[t4][0]);
            float p1 = exp2f(st[t4][1]);
            float p2 = exp2f(st[t4][2]);
            float p3 = exp2f(st[t4][3]);
            rsum += (p0 + p1) + (p2 + p3);
            unsigned d0, d1;
            asm("v_cvt_pk_bf16_f32 %0, %1, %2" : "=v"(d0) : "v"(p0), "v"(p1));
            asm("v_cvt_pk_bf16_f32 %0, %1, %2" : "=v"(d1) : "v"(p2), "v"(p3));
            int kcw = t4 * 2 + (l4 >> 1);
            uint2 w; w.x = d0; w.y = d1;
            *reinterpret_cast<uint2*>(Plw + l15 * 128 + ((kcw ^ (l15 & 7)) * 16) + (l4 & 1) * 8) = w;
        }
        rsum += __shfl_xor(rsum, 16);
        rsum += __shfl_xor(rsum, 32);
        lR += rsum;
#pragma unroll
        for (int kstep = 0; kstep < 2; ++kstep) {
            int kcr = kstep * 4 + l4;
            s16x8 pf = *reinterpret_cast<const s16x8*>(Plw + l15 * 128 + ((kcr ^ (l15 & 7)) * 16));
            s16x8 vf0 = *reinterpret_cast<const s16x8*>((char*)Vl + l15 * 128 + ((kcr ^ (l15 & 7)) * 16));
            s16x8 vf1 = *reinterpret_cast<const s16x8*>((char*)Vl + (16 + l15) * 128 + ((kcr ^ (l15 & 7)) * 16));
            o0 = mfma16(pf, vf0, o0);
            o1 = mfma16(pf, vf1, o1);
        }
    }
    float li[4];
#pragma unroll
    for (int r = 0; r < 4; ++r) li[r] = 1.0f / __shfl(lR, l4 * 4 + r);
#pragma unroll
    for (int r = 0; r < 4; ++r) {
        size_t row = ((size_t)ks * Mtok + voxof(blk, q0 + l4 * 4 + r, logs, lbsz)) * 256 + h * 32;
        Opart[row + l15] = f2b(o0[r] * li[r]);
        Opart[row + 16 + l15] = f2b(o1[r] * li[r]);
    }
    if (l4 == 0) ML[((size_t)ks * Mtok + qvox) * 8 + h] = lR;
}

// Fused intra z0+z1 attention, flat 1D grid of 4096 WGs.
// plane0 (z=0): bid<2048: 64 xb x 4 ks x (1 blk x 8 h) = 2048
// plane1 (z=1): bid>=2048: 8 xb x 4 ks x (8 blk x 8 h) = 2048
__global__ __launch_bounds__(256) void attn_fused01_k(
    const unsigned short* __restrict__ QKVA2, const unsigned short* __restrict__ VtgA,
    unsigned short* __restrict__ OpartI, float* __restrict__ MLbuf) {
    __shared__ unsigned short Kl[2048];
    __shared__ unsigned short Vl[2048];
    __shared__ unsigned short Pl[4096];
    int bid = blockIdx.x;
    int plane, xb, ks, zz, L, logs, lbsz;
    if (bid < 2048) {
        plane = 0; xb = bid & 63; ks = (bid >> 6) & 3; zz = bid >> 8;
        L = 4096; logs = 0; lbsz = 4;
    } else {
        int b2 = bid - 2048;
        plane = 1; xb = b2 & 7; ks = (b2 >> 3) & 3; zz = b2 >> 5;
        L = 512; logs = 1; lbsz = 3;
    }
    const int blk = zz >> 3, h = zz & 7;
    const int wave = threadIdx.x >> 6;
    const int q0 = xb * 64 + wave * 16;
    attn_core<0>(QKVA2 + (size_t)plane * 3145728, VtgA + (size_t)plane * 1048576,
                 OpartI + (size_t)plane * 4194304, MLbuf + (size_t)plane * 131072,
                 L, 4096, logs, lbsz, blk, h, 4, ks, q0, Kl, Vl, Pl);
}

// Generic MFMA attention: grid (L/64, KS, nblk*8). KS==1 -> Opart IS final O.
template <int VST>
__global__ __launch_bounds__(256) void attn_mfma2_k(
    const unsigned short* __restrict__ QKV, const unsigned short* __restrict__ Vtg,
    unsigned short* __restrict__ Opart, float* __restrict__ ML,
    int L, int Mtok, int logs, int lbsz) {
    __shared__ unsigned short Kl[2048];
    __shared__ unsigned short Vl[2048];
    __shared__ unsigned short Pl[4096];
    const int blk = blockIdx.z >> 3, h = blockIdx.z & 7;
    const int wave = threadIdx.x >> 6;
    const int q0 = blockIdx.x * 64 + wave * 16;
    attn_core<VST>(QKV, Vtg, Opart, ML, L, Mtok, logs, lbsz,
                   blk, h, gridDim.y, blockIdx.y, q0, Kl, Vl, Pl);
}

// combine: O = sum_ks l*o_norm / sum_ks l
__global__ __launch_bounds__(256) void attn_combine_k(
    const unsigned short* __restrict__ Opart, const float* __restrict__ ML,
    unsigned short* __restrict__ O, int TotTok, int KS,
    long zOp, long zML, long zO) {
    int z = blockIdx.y, row = blockIdx.x, c = threadIdx.x, h = c >> 5;
    Opart += (size_t)z * zOp;
    ML += (size_t)z * zML;
    O += (size_t)z * zO;
    float osum = 0.f, lsum = 0.f;
    for (int ks = 0; ks < KS; ++ks) {
        float l = ML[((size_t)ks * TotTok + row) * 8 + h];
        lsum += l;
        osum += l * b2f(Opart[((size_t)ks * TotTok + row) * 256 + c]);
    }
    O[(size_t)row * 256 + c] = f2b(osum / lsum);
}

// ---------------------------------------------------------------------------
// fp32 fixed-m attention, intra split z=3 only (L=8). grid (1, 4096).
// Q pre-scaled -> p = exp2(S).
// ---------------------------------------------------------------------------
__global__ __launch_bounds__(256) void attn_f32z3_k(const unsigned short* __restrict__ QKV,
                                                    unsigned short* __restrict__ O) {
    const int y = blockIdx.y;
    const int blk = y >> 3, h = y & 7;
    const int L = 8, logs = 3, lbsz = 1;
    const int tid = threadIdx.x, r = tid >> 3, li = tid & 7;
    const int qr = r;
    const int qrc = (qr < L) ? qr : 0;
    const int qvox = voxof(blk, qrc, logs, lbsz);

    float q[32];
    {
        const unsigned short* qp = QKV + (size_t)qvox * 768 + h * 32;
#pragma unroll
        for (int d8 = 0; d8 < 4; ++d8) {
            s16x8 v = *reinterpret_cast<const s16x8*>(qp + d8 * 8);
#pragma unroll
            for (int e = 0; e < 8; ++e) q[d8 * 8 + e] = b2f((unsigned short)v[e]);
        }
    }
    float l = 0.f;
    float o[32];
#pragma unroll
    for (int d = 0; d < 32; ++d) o[d] = 0.f;

    __shared__ float Kl[32][36];
    __shared__ float Vl[32][36];
    const int krow = tid >> 3, kd = (tid & 7) * 4;
    float4 kv = make_float4(0.f, 0.f, 0.f, 0.f);
    float4 vv = make_float4(0.f, 0.f, 0.f, 0.f);
    if (krow < L) {
        int kvox = voxof(blk, krow, logs, lbsz);
        s16x4 k4 = *reinterpret_cast<const s16x4*>(QKV + (size_t)kvox * 768 + 256 + h * 32 + kd);
        s16x4 v4 = *reinterpret_cast<const s16x4*>(QKV + (size_t)kvox * 768 + 512 + h * 32 + kd);
        kv = make_float4(b2f((unsigned short)k4[0]), b2f((unsigned short)k4[1]),
                         b2f((unsigned short)k4[2]), b2f((unsigned short)k4[3]));
        vv = make_float4(b2f((unsigned short)v4[0]), b2f((unsigned short)v4[1]),
                         b2f((unsigned short)v4[2]), b2f((unsigned short)v4[3]));
    }
    __syncthreads();
    Kl[krow][kd + 0] = kv.x; Kl[krow][kd + 1] = kv.y;
    Kl[krow][kd + 2] = kv.z; Kl[krow][kd + 3] = kv.w;
    Vl[krow][kd + 0] = vv.x; Vl[krow][kd + 1] = vv.y;
    Vl[krow][kd + 2] = vv.z; Vl[krow][kd + 3] = vv.w;
    __syncthreads();
#pragma unroll
    for (int j = 0; j < 4; ++j) {
        int kk = j * 8 + li;
        float acc = 0.f;
#pragma unroll
        for (int d4 = 0; d4 < 8; ++d4) {
            float4 k4 = *reinterpret_cast<const float4*>(&Kl[kk][d4 * 4]);
            acc += q[d4 * 4 + 0] * k4.x + q[d4 * 4 + 1] * k4.y +
                   q[d4 * 4 + 2] * k4.z + q[d4 * 4 + 3] * k4.w;
        }
        float p = (kk < L) ? exp2f(acc) : 0.f;
        l += p;
#pragma unroll
        for (int d4 = 0; d4 < 8; ++d4) {
            float4 v4 = *reinterpret_cast<const float4*>(&Vl[kk][d4 * 4]);
            o[d4 * 4 + 0] += p * v4.x; o[d4 * 4 + 1] += p * v4.y;
            o[d4 * 4 + 2] += p * v4.z; o[d4 * 4 + 3] += p * v4.w;
        }
    }
#pragma unroll
    for (int d = 0; d < 32; ++d) {
        o[d] += __shfl_xor(o[d], 1);
        o[d] += __shfl_xor(o[d], 2);
        o[d] += __shfl_xor(o[d], 4);
    }
    l += __shfl_xor(l, 1);
    l += __shfl_xor(l, 2);
    l += __shfl_xor(l, 4);
    if (qr < L) {
        float inv = 1.0f / l;
        size_t orow = (size_t)qvox * 256 + h * 32;
#pragma unroll
        for (int qd = 0; qd < 4; ++qd) O[orow + li * 4 + qd] = f2b(o[li * 4 + qd] * inv);
    }
}

// ---------------------------------------------------------------------------
// fp32 fixed-m inter attention, z in {0,1,2} (L={1,8,64}), identity map.
// Q pre-scaled -> p = exp2(S). grid (2, 24): y -> z = y>>3, h = y&7
// ---------------------------------------------------------------------------
__global__ __launch_bounds__(256) void attn_f32b_k(const unsigned short* __restrict__ RQKV,
                                                   unsigned short* __restrict__ RO) {
    const int y = blockIdx.y;
    const int z = y >> 3, h = y & 7;
    const int Lz[3] = {1, 8, 64};
    const int goffc[3] = {0, 1, 9};
    const int L = Lz[z];
    const unsigned short* base = RQKV + (size_t)goffc[z] * 768;
    unsigned short* O = RO + (size_t)goffc[z] * 256;
    const int tid = threadIdx.x;
    const int r = tid >> 3, li = tid & 7;
    const int qr = blockIdx.x * 32 + r;
    const int qrc = (qr < L) ? qr : 0;

    float q[32];
    {
        const unsigned short* qp = base + (size_t)qrc * 768 + h * 32;
#pragma unroll
        for (int d8 = 0; d8 < 4; ++d8) {
            s16x8 v = *reinterpret_cast<const s16x8*>(qp + d8 * 8);
#pragma unroll
            for (int e = 0; e < 8; ++e) q[d8 * 8 + e] = b2f((unsigned short)v[e]);
        }
    }
    float l = 0.f;
    float o[32];
#pragma unroll
    for (int d = 0; d < 32; ++d) o[d] = 0.f;

    __shared__ float Kl[32][36];
    __shared__ float Vl[32][36];
    const int krow = tid >> 3, kd = (tid & 7) * 4;
    const int nt = (L + 31) / 32;
    for (int kt = 0; kt < nt; ++kt) {
        int key = kt * 32 + krow;
        float4 kv = make_float4(0.f, 0.f, 0.f, 0.f);
        float4 vv = make_float4(0.f, 0.f, 0.f, 0.f);
        if (key < L) {
            s16x4 k4 = *reinterpret_cast<const s16x4*>(base + (size_t)key * 768 + 256 + h * 32 + kd);
            s16x4 v4 = *reinterpret_cast<const s16x4*>(base + (size_t)key * 768 + 512 + h * 32 + kd);
            kv = make_float4(b2f((unsigned short)k4[0]), b2f((unsigned short)k4[1]),
                             b2f((unsigned short)k4[2]), b2f((unsigned short)k4[3]));
            vv = make_float4(b2f((unsigned short)v4[0]), b2f((unsigned short)v4[1]),
                             b2f((unsigned short)v4[2]), b2f((unsigned short)v4[3]));
        }
        __syncthreads();
        Kl[krow][kd + 0] = kv.x; Kl[krow][kd + 1] = kv.y;
        Kl[krow][kd + 2] = kv.z; Kl[krow][kd + 3] = kv.w;
        Vl[krow][kd + 0] = vv.x; Vl[krow][kd + 1] = vv.y;
        Vl[krow][kd + 2] = vv.z; Vl[krow][kd + 3] = vv.w;
        __syncthreads();
#pragma unroll
        for (int j = 0; j < 4; ++j) {
            int kk = j * 8 + li;
            float acc = 0.f;
#pragma unroll
            for (int d4 = 0; d4 < 8; ++d4) {
                float4 k4 = *reinterpret_cast<const float4*>(&Kl[kk][d4 * 4]);
                acc += q[d4 * 4 + 0] * k4.x + q[d4 * 4 + 1] * k4.y +
                       q[d4 * 4 + 2] * k4.z + q[d4 * 4 + 3] * k4.w;
            }
            float p = (kt * 32 + kk < L) ? exp2f(acc) : 0.f;
            l += p;
#pragma unroll
            for (int d4 = 0; d4 < 8; ++d4) {
                float4 v4 = *reinterpret_cast<const float4*>(&Vl[kk][d4 * 4]);
                o[d4 * 4 + 0] += p * v4.x; o[d4 * 4 + 1] += p * v4.y;
                o[d4 * 4 + 2] += p * v4.z; o[d4 * 4 + 3] += p * v4.w;
            }
        }
    }
#pragma unroll
    for (int d = 0; d < 32; ++d) {
        o[d] += __shfl_xor(o[d], 1);
        o[d] += __shfl_xor(o[d], 2);
        o[d] += __shfl_xor(o[d], 4);
    }
    l += __shfl_xor(l, 1);
    l += __shfl_xor(l, 2);
    l += __shfl_xor(l, 4);
    if (qr < L) {
        float inv = 1.0f / l;
        size_t orow = (size_t)qr * 256 + h * 32;
#pragma unroll
        for (int qd = 0; qd < 4; ++qd) O[orow + li * 4 + qd] = f2b(o[li * 4 + qd] * inv);
    }
}

// ---------------------------------------------------------------------------
// intra residual+LN, batched: grid 4*4096; T1 bf16 in, T bf16 out
// ---------------------------------------------------------------------------
__global__ __launch_bounds__(256) void add_ln_b_k(const float* __restrict__ X,
                                                  const unsigned short* __restrict__ T1b,
                                                  const float* __restrict__ g,
                                                  const float* __restrict__ b,
                                                  unsigned short* __restrict__ Tb) {
    int row = blockIdx.x & 4095, z = blockIdx.x >> 12, t = threadIdx.x;
    float v = X[row * 256 + t] + b2f(T1b[(size_t)z * 1048576 + row * 256 + t]);
    float s1 = v, s2 = v * v;
#pragma unroll
    for (int mask = 1; mask < 64; mask <<= 1) {
        s1 += __shfl_xor(s1, mask);
        s2 += __shfl_xor(s2, mask);
    }
    __shared__ float w1[4], w2[4];
    int wv = t >> 6, ln = t & 63;
    if (ln == 0) { w1[wv] = s1; w2[wv] = s2; }
    __syncthreads();
    float tot1 = w1[0] + w1[1] + w1[2] + w1[3];
    float tot2 = w2[0] + w2[1] + w2[2] + w2[3];
    float mean = tot1 * (1.0f / 256.0f);
    float var = tot2 * (1.0f / 256.0f) - mean * mean;
    float rstd = rsqrtf(var + 1e-5f);
    Tb[(size_t)z * 1048576 + row * 256 + t] =
        f2b((v - mean) * rstd * g[z * 256 + t] + b[z * 256 + t]);
}

// batched inter residual+LN over all 585 rows
__global__ __launch_bounds__(256) void add_ln_i_k(const float* __restrict__ Rb_all,
                                                  const float* __restrict__ R1_all,
                                                  const float* __restrict__ g,
                                                  const float* __restrict__ b,
                                                  float* __restrict__ RLN_all) {
    int row = blockIdx.x, t = threadIdx.x;
    int z = (row == 0) ? 0 : (row < 9 ? 1 : (row < 73 ? 2 : 3));
    float v = Rb_all[row * 256 + t] + R1_all[row * 256 + t];
    float s1 = v, s2 = v * v;
#pragma unroll
    for (int mask = 1; mask < 64; mask <<= 1) {
        s1 += __shfl_xor(s1, mask);
        s2 += __shfl_xor(s2, mask);
    }
    __shared__ float w1[4], w2[4];
    int wv = t >> 6, ln = t & 63;
    if (ln == 0) { w1[wv] = s1; w2[wv] = s2; }
    __syncthreads();
    float tot1 = w1[0] + w1[1] + w1[2] + w1[3];
    float tot2 = w2[0] + w2[1] + w2[2] + w2[3];
    float mean = tot1 * (1.0f / 256.0f);
    float var = tot2 * (1.0f / 256.0f) - mean * mean;
    float rstd = rsqrtf(var + 1e-5f);
    RLN_all[row * 256 + t] = (v - mean) * rstd * g[z * 256 + t] + b[z * 256 + t];
}

// batched block means from bf16 T, bounded contention; grid 896
__global__ __launch_bounds__(256) void block_mean_b_k(const unsigned short* __restrict__ Tb_all,
                                                      float* __restrict__ Rb_all) {
    int bx = blockIdx.x, c = threadIdx.x;
    int z, blk, ch, rpc;
    float inv_bs;
    if (bx < 128)      { z = 0; blk = 0;               ch = bx;              rpc = 32; inv_bs = 1.0f / 4096.0f; }
    else if (bx < 256) { int l = bx - 128; z = 1; blk = l >> 4; ch = l & 15; rpc = 32; inv_bs = 1.0f / 512.0f; }
    else if (bx < 384) { int l = bx - 256; z = 2; blk = l >> 1; ch = l & 1;  rpc = 32; inv_bs = 1.0f / 64.0f; }
    else               { int l = bx - 384; z = 3; blk = l;      ch = 0;      rpc = 8;  inv_bs = 1.0f / 8.0f; }
    const int goffc[4] = {0, 1, 9, 73};
    const int logs = z, lbsz = 4 - z;
    const unsigned short* T = Tb_all + (size_t)z * 1048576;
    float* R = Rb_all + (size_t)(goffc[z] + blk) * 256;
    int p0 = ch * rpc;
    float sum = 0.f;
    for (int p = p0; p < p0 + rpc; ++p)
        sum += b2f(T[(size_t)voxof(blk, p, logs, lbsz) * 256 + c]);
    atomicAdd(&R[c], sum * inv_bs);
}

// BN stats over Yt [4096 vox][256 ch]
__global__ __launch_bounds__(256) void bn_stats_k(const float* __restrict__ Yt,
                                                  float* __restrict__ MV) {
    int b0 = blockIdx.x * 16, c = threadIdx.x;
    float s1 = 0.f, s2 = 0.f;
#pragma unroll
    for (int j = 0; j < 16; ++j) {
        float v = Yt[(size_t)(b0 + j) * 256 + c];
        s1 += v; s2 += v * v;
    }
    atomicAdd(&MV[c], s1);
    atomicAdd(&MV[256 + c], s2);
}

__global__ __launch_bounds__(256) void bn_apply_k(const float* __restrict__ Yt,
                                                  const float* __restrict__ MV,
                                                  const float* __restrict__ g,
                                                  const float* __restrict__ b,
                                                  float* __restrict__ outp) {
    int c = blockIdx.x, t = threadIdx.x;
    float mean = MV[c] * (1.0f / 4096.0f);
    float var = MV[256 + c] * (1.0f / 4096.0f) - mean * mean;
    float rstd = rsqrtf(var + 1e-5f);
    float gg = g[c] * rstd, bb = b[c] - mean * gg;
    for (int it = 0; it < 16; ++it) {
        int v = it * 256 + t;
        float y = Yt[(size_t)v * 256 + c];
        float rr = y * gg + bb;
        outp[(size_t)c * 4096 + v] = rr > 0.f ? rr : 0.f;
    }
}

// ---------------------------------------------------------------------------
extern "C" void kernel_launch(void* const* d_in, const int* in_sizes, int n_in,
                              void* d_out, int out_size, void* d_ws, size_t ws_size,
                              hipStream_t stream) {
    (void)in_sizes; (void)n_in; (void)out_size; (void)ws_size;
    const float* x          = (const float*)d_in[0];
    const float* intra_bqkv = (const float*)d_in[2];
    const float* intra_bout = (const float*)d_in[4];
    const float* intra_ln_g = (const float*)d_in[5];
    const float* intra_ln_b = (const float*)d_in[6];
    const float* inter_bqkv = (const float*)d_in[8];
    const float* inter_bout = (const float*)d_in[10];
    const float* inter_ln_g = (const float*)d_in[11];
    const float* inter_ln_b = (const float*)d_in[12];
    const float* ffn_b1     = (const float*)d_in[14];
    const float* ffn_b2     = (const float*)d_in[16];
    const float* bn_g       = (const float*)d_in[18];
    const float* bn_b       = (const float*)d_in[19];
    float* out = (float*)d_out;

    float* ws = (float*)d_ws;
    unsigned short* OUTt  = (unsigned short*)ws;                  // 2,097,152 f
    float* Xt             = ws + 2097152;                         // 1,048,576
    unsigned short* Xtb   = (unsigned short*)(ws + 3145728);      // 524,288
    unsigned short* QKVA2 = (unsigned short*)(ws + 3670016);      // [2][4096][768]
    unsigned short* ObfA  = (unsigned short*)(ws + 6815744);      // [4][4096][256]
    unsigned short* T1A   = (unsigned short*)(ws + 8912896);      // [4][4096][256] bf16
    unsigned short* TAb   = (unsigned short*)(ws + 11010048);     // [4][4096][256] bf16
    float* Rb_all         = ws + 13107200;                        // 149,760
    unsigned short* RQKVa = (unsigned short*)(ws + 13256960);     // 449,280 sh
    unsigned short* RObA  = (unsigned short*)(ws + 13481600);     // 149,760 sh
    float* R1A            = ws + 13556480;                        // 149,760
    float* RLN_all        = ws + 13706240;                        // 149,760
    unsigned short* WB    = (unsigned short*)(ws + 13856000);     // 3,407,872 sh
    unsigned short* VtgA  = (unsigned short*)(ws + 15559936);     // [2][256][4096]
    unsigned short* Vtgr  = (unsigned short*)(ws + 16608512);     // 131,072 sh
    float* MLbuf          = ws + 16674048;                        // 262,144 f
    // lifetime aliases:
    unsigned short* OpartI = T1A;                 // [2][4][4096][256] bf16 over T1A+TAb
    unsigned short* OpartR = T1A;                 // [8][512][256] bf16 (Phase D)
    unsigned short* HidA   = QKVA2;               // [4][4096][512] bf16 over QKVA2+ObfA
    float* MV              = MLbuf;               // 512 f32 (after attn)
    float* Yt              = Xt;                  // fuse output

    unsigned short* WBq  = WB;
    unsigned short* WBo  = WB + 786432;
    unsigned short* WBiq = WB + 1048576;
    unsigned short* WBio = WB + 1835008;
    unsigned short* WBf1 = WB + 2097152;
    unsigned short* WBf2 = WB + 2621440;
    unsigned short* WBfu = WB + 3145728;

    const long ZC = 1048576;

    prologue_k<<<4499, 256, 0, stream>>>((const float*)d_in[1], (const float*)d_in[3],
                                         (const float*)d_in[7], (const float*)d_in[9],
                                         (const float*)d_in[13], (const float*)d_in[15],
                                         (const float*)d_in[17], WB, x, Xt, Xtb, Rb_all);

    // ---- Phase A: QKV z in {0,1} (batched, V^T, Q pre-scaled) + fused MFMA attn ----
    gemm_k<4, 1, 0, 1, 1, 0, 0, 0, 1><<<dim3(12, 32, 2), 256, 0, stream>>>(
        Xtb, WBq, intra_bqkv, QKVA2, 4096, 768, 256, 768,
        0, 196608, 768, 3145728, VtgA, 4096, 1048576, TAb, Rb_all, Xt);
    attn_fused01_k<<<4096, 256, 0, stream>>>(QKVA2, VtgA, OpartI, MLbuf);
    attn_combine_k<<<dim3(4096, 2), 256, 0, stream>>>(
        OpartI, MLbuf, ObfA, 4096, 4, 4194304, 131072, 1048576);
    // ---- QKV z in {2,3} (batched, V^T, Q pre-scaled) + MFMA z2 (VST=1) + f32 z3 ----
    gemm_k<4, 1, 0, 1, 1, 0, 0, 0, 1><<<dim3(12, 32, 2), 256, 0, stream>>>(
        Xtb, WBq + 2 * 196608, intra_bqkv + 2 * 768, QKVA2, 4096, 768, 256, 768,
        0, 196608, 768, 3145728, VtgA, 4096, 1048576, TAb, Rb_all, Xt);
    attn_mfma2_k<1><<<dim3(1, 1, 512), 256, 0, stream>>>(
        QKVA2, VtgA, ObfA + 2 * ZC, MLbuf, 64, 4096, 2, 2);
    attn_f32z3_k<<<dim3(1, 4096), 256, 0, stream>>>(QKVA2 + 3145728, ObfA + 3 * ZC);
    // ---- Phase B: batched out-projection -> T1A (bf16), BM=128 ----
    gemm_k<4, 1, 0, 1, 0, 0, 0, 0, 0><<<dim3(4, 32, 4), 256, 0, stream>>>(
        ObfA, WBo, intra_bout, T1A, 4096, 256, 256, 256,
        ZC, 65536, 256, ZC, nullptr, 0, 0, TAb, Rb_all, Xt);
    // ---- Phase C: batched residual+LN -> TAb; block means -> Rb_all ----
    add_ln_b_k<<<16384, 256, 0, stream>>>(Xt, T1A, intra_ln_g, intra_ln_b, TAb);
    block_mean_b_k<<<896, 256, 0, stream>>>(TAb, Rb_all);
    // ---- Phase D: inter chain (Q pre-scaled in D1) ----
    gemm_k<2, 1, 0, 1, 1, 1, 0, 2, 1><<<dim3(12, 8, 4), 256, 0, stream>>>(
        Rb_all, WBiq, inter_bqkv, RQKVa, 512, 768, 256, 768,
        0, 196608, 768, 0, Vtgr, 512, 0, TAb, Rb_all, Xt);
    attn_mfma2_k<0><<<dim3(8, 8, 8), 256, 0, stream>>>(
        RQKVa + (size_t)73 * 768, Vtgr, OpartR, MLbuf, 512, 512, 0, 4);
    attn_f32b_k<<<dim3(2, 24), 256, 0, stream>>>(RQKVa, RObA);
    attn_combine_k<<<dim3(512, 1), 256, 0, stream>>>(
        OpartR, MLbuf, RObA + (size_t)73 * 256, 512, 8, 0, 0, 0);
    gemm_k<2, 1, 0, 0, 0, 0, 0, 2, 0><<<dim3(4, 8, 4), 256, 0, stream>>>(
        RObA, WBio, inter_bout, R1A, 512, 256, 256, 256,
        0, 65536, 256, 0, nullptr, 0, 0, TAb, Rb_all, Xt);
    add_ln_i_k<<<585, 256, 0, stream>>>(Rb_all, R1A, inter_ln_g, inter_ln_b, RLN_all);
    // ---- Phase E: batched FFN1 (bf16 T + RLN fused A, GELU) -> HidA ----
    gemm_k<4, 1, 1, 1, 0, 3, 0, 1, 0><<<dim3(8, 32, 4), 256, 0, stream>>>(
        TAb, WBf1, ffn_b1, HidA, 4096, 512, 256, 512,
        ZC, 131072, 512, 2097152, nullptr, 0, 0, TAb, RLN_all, Xt);
    // ---- Phase F: batched FFN2 (+T+RLN+X residuals) -> OUTt columns, BM=128 ----
    gemm_k<4, 1, 0, 1, 0, 0, 1, 1, 0><<<dim3(4, 32, 4), 256, 0, stream>>>(
        HidA, WBf2, ffn_b2, OUTt, 4096, 256, 512, 1024,
        2097152, 131072, 256, 256, nullptr, 0, 0, TAb, RLN_all, Xt);
    // ---- Phase G: fuse conv + BN + ReLU, BM=128 ----
    gemm_k<4, 0, 0, 0, 0, 0, 0, 0, 0><<<dim3(4, 32, 1), 256, 0, stream>>>(
        OUTt, WBfu, nullptr, Yt, 4096, 256, 1024, 256,
        0, 0, 0, 0, nullptr, 0, 0, TAb, Rb_all, Xt);
    hipMemsetAsync(MV, 0, 512 * sizeof(float), stream);
    bn_stats_k<<<256, 256, 0, stream>>>(Yt, MV);
    bn_apply_k<<<256, 256, 0, stream>>>(Yt, MV, bn_g, bn_b, out);
}

// Round 18
// 261.605 us; speedup vs baseline: 1.0346x; 1.0346x over previous
//
#include <hip/hip_runtime.h>
#include <math.h>

typedef __attribute__((ext_vector_type(8))) short s16x8;
typedef __attribute__((ext_vector_type(4))) short s16x4;
typedef __attribute__((ext_vector_type(4))) float f32x4;

__device__ __forceinline__ float b2f(unsigned short u) {
    union { unsigned u; float f; } x;
    x.u = ((unsigned)u) << 16;
    return x.f;
}
__device__ __forceinline__ unsigned short f2b(float f) {
    union { float f; unsigned u; } x;
    x.f = f;
    unsigned u = x.u;
    return (unsigned short)((u + 0x7FFFu + ((u >> 16) & 1u)) >> 16);
}
__device__ __forceinline__ f32x4 mfma16(s16x8 a, s16x8 b, f32x4 c) {
    return __builtin_amdgcn_mfma_f32_16x16x32_bf16(a, b, c, 0, 0, 0);
}
__device__ __forceinline__ float gelu_exact(float x) {
    return 0.5f * x * (1.0f + erff(x * 0.70710678118654752440f));
}
__device__ __forceinline__ void gload_lds16(const void* g, void* l) {
    __builtin_amdgcn_global_load_lds(
        (const __attribute__((address_space(1))) unsigned int*)g,
        (__attribute__((address_space(3))) unsigned int*)l, 16, 0, 0);
}
// raster voxel of (block, position) for split s=1<<logs, bsz=1<<lbsz
__device__ __forceinline__ int voxof(int blk, int pos, int logs, int lbsz) {
    int bm = (1 << lbsz) - 1, sm = (1 << logs) - 1;
    int ix = pos & bm, iy = (pos >> lbsz) & bm, iz = pos >> (2 * lbsz);
    int gx = blk & sm, gy = (blk >> logs) & sm, gz = blk >> (2 * logs);
    return (((gz << lbsz) + iz) << 8) + (((gy << lbsz) + iy) << 4) + ((gx << lbsz) + ix);
}
__device__ __forceinline__ int blkof(int v, int logs, int lbsz) {
    int gx = (v & 15) >> lbsz, gy = ((v >> 4) & 15) >> lbsz, gz = ((v >> 8) & 15) >> lbsz;
    return (((gz << logs) + gy) << logs) + gx;
}

// ---------------------------------------------------------------------------
// Prologue: weights->bf16 (bx<3328), x transpose (bx<4352), Rb zero (rest)
// ---------------------------------------------------------------------------
__global__ __launch_bounds__(256) void prologue_k(
    const float* w0, const float* w1, const float* w2, const float* w3,
    const float* w4, const float* w5, const float* w6,
    unsigned short* __restrict__ wdst, const float* __restrict__ x,
    float* __restrict__ Xt, unsigned short* __restrict__ Xtb,
    float* __restrict__ Rb) {
    __shared__ float tile[32][33];
    int bx = blockIdx.x;
    if (bx < 3328) {
        int i = (bx * 256 + threadIdx.x) * 4;
        const float* s; int off;
        if (i < 786432)        { s = w0; off = 0; }
        else if (i < 1048576)  { s = w1; off = 786432; }
        else if (i < 1835008)  { s = w2; off = 1048576; }
        else if (i < 2097152)  { s = w3; off = 1835008; }
        else if (i < 2621440)  { s = w4; off = 2097152; }
        else if (i < 3145728)  { s = w5; off = 2621440; }
        else                   { s = w6; off = 3145728; }
        float4 v = *reinterpret_cast<const float4*>(s + (i - off));
        wdst[i + 0] = f2b(v.x); wdst[i + 1] = f2b(v.y);
        wdst[i + 2] = f2b(v.z); wdst[i + 3] = f2b(v.w);
    } else if (bx < 4352) {
        int t = bx - 3328;
        int v0 = (t & 127) * 32, c0 = (t >> 7) * 32;
        int tx = threadIdx.x & 31, ty = threadIdx.x >> 5;
#pragma unroll
        for (int j = 0; j < 32; j += 8)
            tile[ty + j][tx] = x[(size_t)(c0 + ty + j) * 4096 + v0 + tx];
        __syncthreads();
#pragma unroll
        for (int j = 0; j < 32; j += 8) {
            float v = tile[tx][ty + j];
            size_t o = (size_t)(v0 + ty + j) * 256 + c0 + tx;
            Xt[o] = v;
            Xtb[o] = f2b(v);
        }
    } else {
        int idx = ((bx - 4352) * 256 + threadIdx.x) * 4;
        if (idx < 149760) {
            float4 z4 = make_float4(0.f, 0.f, 0.f, 0.f);
            *reinterpret_cast<float4*>(Rb + idx) = z4;
        }
    }
}

// ---------------------------------------------------------------------------
// bf16 MFMA GEMM, BM=32*MFR, BN=64, BK=64, 256 thr (4 waves 2x2), z-batched.
// AF32: 0 = A bf16 gload_lds; 1 = A f32 reg-staged;
//       2 = A f32 + RLN[blk] (ZS=1); 3 = A bf16 + RLN[blk] (ZS=1)
// EPI:  1 = FFN2: v += bf16 T[z] + RLN[goff+blk] + X; write bf16
// VT:   n in [512,768) also to vt[z*zsV + (n-512)*mtot + m]
// ZS:   1 = per-split mode (logs=z); 2 = inter mode (M={1,8,64,512}[z], goff rows)
// QSC:  1 = scale Q columns (n<256) by cscale = log2(e)/sqrt(32)
// ---------------------------------------------------------------------------
template <int MFR, int HASB, int ACT, int OBF, int VT, int AF32, int EPI, int ZS, int QSC>
__global__ __launch_bounds__(256) void gemm_k(
    const void* __restrict__ Aptr, const unsigned short* __restrict__ W,
    const float* __restrict__ bias, void* __restrict__ outp,
    int M, int N, int K, int ldC,
    long zsA, long zsW, long zsB, long zsC,
    unsigned short* __restrict__ vt, int mtot, long zsV,
    const void* __restrict__ Tresv, const float* __restrict__ RLNres,
    const float* __restrict__ Xres) {
    constexpr int BM = 32 * MFR;
    __shared__ unsigned short As[BM * 64];
    __shared__ unsigned short Ws[64 * 64];
    const int z = blockIdx.z;
    const int logs = (ZS == 1) ? z : 0;
    const int lbsz = (ZS == 1) ? (4 - z) : 4;
    const int goffc[4] = {0, 1, 9, 73};
    const int Mzc[4] = {1, 8, 64, 512};
    const int Me = (ZS == 2) ? Mzc[z] : M;
    const int m0 = blockIdx.y * BM, n0 = blockIdx.x * 64;
    if (ZS == 2 && m0 >= Me) return;
    const unsigned short* Ab = (const unsigned short*)Aptr +
        ((AF32 == 0 || AF32 == 3) ? ((size_t)z * zsA + (ZS == 2 ? (size_t)goffc[z] * K : 0)) : 0);
    const float* Af = (const float*)Aptr +
        ((AF32 == 1 || AF32 == 2) ? ((size_t)z * zsA + (ZS == 2 ? (size_t)goffc[z] * K : 0)) : 0);
    W += (size_t)z * zsW;
    const float* biasz = bias + (HASB ? (size_t)z * zsB : 0);
    char* outc = (char*)outp +
        ((size_t)z * zsC + (ZS == 2 ? (size_t)goffc[z] * ldC : 0)) * ((OBF || EPI) ? 2 : 4);
    const float* RLNz = RLNres + (ZS == 1 ? goffc[z] * 256 : 0);
    const unsigned short* Tzb = (const unsigned short*)Tresv + (ZS == 1 ? (size_t)z * 1048576 : 0);

    const int tid = threadIdx.x;
    const int wave = tid >> 6, lane = tid & 63;
    const int l15 = lane & 15, l4 = lane >> 4;
    const int wr = wave >> 1, wc = wave & 1;
    const int srow = lane >> 3;
    const int schunk = (lane & 7) ^ srow;
    f32x4 acc[MFR][2] = {};
    for (int k0 = 0; k0 < K; k0 += 64) {
        s16x8 sreg[MFR];
        if (AF32) {
#pragma unroll
            for (int i = 0; i < MFR; ++i) {
                int ca = wave * MFR + i;
                int gr = m0 + ca * 8 + srow;
                gr = gr < Me ? gr : (Me - 1);
                s16x8 pk;
                if (AF32 == 3) {
                    s16x8 tb = *reinterpret_cast<const s16x8*>(Ab + (size_t)gr * K + k0 + schunk * 8);
                    const float* rl = RLNz + (size_t)blkof(gr, logs, lbsz) * 256 + k0 + schunk * 8;
#pragma unroll
                    for (int e = 0; e < 8; ++e) pk[e] = (short)f2b(b2f((unsigned short)tb[e]) + rl[e]);
                } else {
                    const float* src = Af + (size_t)gr * K + k0 + schunk * 8;
                    float4 u = *reinterpret_cast<const float4*>(src);
                    float4 w2 = *reinterpret_cast<const float4*>(src + 4);
                    if (AF32 == 2) {
                        const float* rl = RLNz + (size_t)blkof(gr, logs, lbsz) * 256 + k0 + schunk * 8;
                        float4 a = *reinterpret_cast<const float4*>(rl);
                        float4 b = *reinterpret_cast<const float4*>(rl + 4);
                        u.x += a.x; u.y += a.y; u.z += a.z; u.w += a.w;
                        w2.x += b.x; w2.y += b.y; w2.z += b.z; w2.w += b.w;
                    }
                    pk[0] = (short)f2b(u.x); pk[1] = (short)f2b(u.y);
                    pk[2] = (short)f2b(u.z); pk[3] = (short)f2b(u.w);
                    pk[4] = (short)f2b(w2.x); pk[5] = (short)f2b(w2.y);
                    pk[6] = (short)f2b(w2.z); pk[7] = (short)f2b(w2.w);
                }
                sreg[i] = pk;
            }
        }
        __syncthreads();
        if (AF32) {
#pragma unroll
            for (int i = 0; i < MFR; ++i) {
                int ca = wave * MFR + i;
                *reinterpret_cast<s16x8*>((char*)As + ca * 1024 + lane * 16) = sreg[i];
            }
        } else {
#pragma unroll
            for (int i = 0; i < MFR; ++i) {
                int ca = wave * MFR + i;
                int gr = m0 + ca * 8 + srow;
                gr = gr < Me ? gr : (Me - 1);
                gload_lds16(Ab + (size_t)gr * K + k0 + schunk * 8, (char*)As + ca * 1024);
            }
        }
#pragma unroll
        for (int i = 0; i < 2; ++i) {
            int cb = wave * 2 + i;
            int gr = n0 + cb * 8 + srow;
            gload_lds16(W + (size_t)gr * K + k0 + schunk * 8, (char*)Ws + cb * 1024);
        }
        asm volatile("s_waitcnt vmcnt(0)" ::: "memory");
        __syncthreads();
#pragma unroll
        for (int ks = 0; ks < 2; ++ks) {
            s16x8 af[MFR], bf[2];
#pragma unroll
            for (int mf = 0; mf < MFR; ++mf) {
                int row = wr * (MFR * 16) + mf * 16 + l15;
                int ch = (ks * 4 + l4) ^ (row & 7);
                af[mf] = *reinterpret_cast<const s16x8*>((char*)As + row * 128 + ch * 16);
            }
#pragma unroll
            for (int nf = 0; nf < 2; ++nf) {
                int row = wc * 32 + nf * 16 + l15;
                int ch = (ks * 4 + l4) ^ (row & 7);
                bf[nf] = *reinterpret_cast<const s16x8*>((char*)Ws + row * 128 + ch * 16);
            }
#pragma unroll
            for (int mf = 0; mf < MFR; ++mf)
#pragma unroll
                for (int nf = 0; nf < 2; ++nf)
                    acc[mf][nf] = mfma16(af[mf], bf[nf], acc[mf][nf]);
        }
    }
#pragma unroll
    for (int nf = 0; nf < 2; ++nf) {
        int n = n0 + wc * 32 + nf * 16 + l15;
        float bv = HASB ? biasz[n] : 0.0f;
#pragma unroll
        for (int mf = 0; mf < MFR; ++mf) {
            float vr[4];
#pragma unroll
            for (int r = 0; r < 4; ++r) {
                int m = m0 + wr * (MFR * 16) + mf * 16 + l4 * 4 + r;
                float v = acc[mf][nf][r] + bv;
                if (ACT == 1) v = gelu_exact(v);
                if (QSC) { if (n < 256) v *= (0.17677669529663687f * 1.44269504088896f); }
                vr[r] = v;
                if (m < Me) {
                    size_t co = (size_t)m * ldC + n;
                    if (EPI == 1) {
                        v += b2f(Tzb[(size_t)m * 256 + n]) +
                             RLNz[(size_t)blkof(m, logs, lbsz) * 256 + n] +
                             Xres[(size_t)m * 256 + n];
                        ((unsigned short*)outc)[co] = f2b(v);
                    } else if (OBF) {
                        ((unsigned short*)outc)[co] = f2b(v);
                    } else {
                        ((float*)outc)[co] = v;
                    }
                }
            }
            if (VT) {
                if ((ZS != 2 || z == 3) && n >= 512) {
                    s16x4 pk;
#pragma unroll
                    for (int r = 0; r < 4; ++r) pk[r] = (short)f2b(vr[r]);
                    int mb = m0 + wr * (MFR * 16) + mf * 16 + l4 * 4;
                    *reinterpret_cast<s16x4*>(vt + (size_t)z * zsV + (size_t)(n - 512) * mtot + mb) = pk;
                }
            }
        }
    }
}

// ---------------------------------------------------------------------------
// Shared MFMA flash-attention tile body (fixed-m softmax, Q pre-scaled so
// P = exp2(S) directly). VST=0: V^T via gload_lds16 (needs 8 consecutive
// positions == 8 consecutive voxels). VST=1: reg-staged 2x4-voxel loads
// (required for lbsz==2, z=2 intra).
// ---------------------------------------------------------------------------
template <int VST>
__device__ __forceinline__ void attn_core(
    const unsigned short* QKV, const unsigned short* Vtg,
    unsigned short* Opart, float* ML,
    int L, int Mtok, int logs, int lbsz,
    int blk, int h, int KS, int ks, int q0,
    unsigned short* Kl, unsigned short* Vl, unsigned short* Pl) {
    const int wave = threadIdx.x >> 6, lane = threadIdx.x & 63;
    const int l15 = lane & 15, l4 = lane >> 4;
    char* Plw = (char*)Pl + wave * 2048;

    const int qvox = voxof(blk, q0 + l15, logs, lbsz);
    s16x8 qf = *reinterpret_cast<const s16x8*>(QKV + (size_t)qvox * 768 + h * 32 + l4 * 8);

    f32x4 o0 = {}, o1 = {};
    float lR = 0.f;

    const int krow = threadIdx.x >> 2, kch = threadIdx.x & 3;
    const int kcol = (kch ^ (krow & 3)) * 8;
    const int vd = threadIdx.x >> 3, vc = threadIdx.x & 7;
    const int vrun = (vc ^ (vd & 7)) * 8;

    const int nt = L / (64 * KS);
    const int kb0 = ks * (L / KS);
    const int vstep = (nt > 1)
        ? (voxof(blk, kb0 + 64, logs, lbsz) - voxof(blk, kb0, logs, lbsz)) : 0;
    const unsigned short* ksrc =
        QKV + (size_t)voxof(blk, kb0 + krow, logs, lbsz) * 768 + 256 + h * 32 + kcol;
    const unsigned short* vsrc =
        Vtg + (size_t)(h * 32 + vd) * Mtok + voxof(blk, kb0 + vrun, logs, lbsz);
    const unsigned short* vsrc2 =
        Vtg + (size_t)(h * 32 + vd) * Mtok + voxof(blk, kb0 + vrun + 4, logs, lbsz);
    const size_t kadv = (size_t)vstep * 768;
    char* kdst = (char*)Kl + wave * 1024;
    char* vdst = (char*)Vl + wave * 1024;

    for (int it = 0; it < nt; ++it) {
        __syncthreads();
        gload_lds16(ksrc, kdst);
        if (VST == 0) {
            gload_lds16(vsrc, vdst);
        } else {
            s16x4 lo = *reinterpret_cast<const s16x4*>(vsrc);
            s16x4 hi = *reinterpret_cast<const s16x4*>(vsrc2);
            s16x8 vv;
            vv[0] = lo[0]; vv[1] = lo[1]; vv[2] = lo[2]; vv[3] = lo[3];
            vv[4] = hi[0]; vv[5] = hi[1]; vv[6] = hi[2]; vv[7] = hi[3];
            *reinterpret_cast<s16x8*>((char*)Vl + threadIdx.x * 16) = vv;
        }
        ksrc += kadv; vsrc += vstep; vsrc2 += vstep;
        asm volatile("s_waitcnt vmcnt(0)" ::: "memory");
        __syncthreads();

        f32x4 st[4];
        const f32x4 zz = {0.f, 0.f, 0.f, 0.f};
#pragma unroll
        for (int t4 = 0; t4 < 4; ++t4) {
            s16x8 kf = *reinterpret_cast<const s16x8*>(
                (char*)Kl + (t4 * 16 + l15) * 64 + ((l4 ^ (l15 & 3)) << 4));
            st[t4] = mfma16(kf, qf, zz);
        }
        float rsum = 0.f;
#pragma unroll
        for (int t4 = 0; t4 < 4; ++t4) {
            float p0 = exp2f(st[t4][0]);
            float p1 = exp2f(st[t4][1]);
            float p2 = exp2f(st[t4][2]);
            float p3 = exp2f(st[t4][3]);
            rsum += (p0 + p1) + (p2 + p3);
            unsigned d0, d1;
            asm("v_cvt_pk_bf16_f32 %0, %1, %2" : "=v"(d0) : "v"(p0), "v"(p1));
            asm("v_cvt_pk_bf16_f32 %0, %1, %2" : "=v"(d1) : "v"(p2), "v"(p3));
            int kcw = t4 * 2 + (l4 >> 1);
            uint2 w; w.x = d0; w.y = d1;
            *reinterpret_cast<uint2*>(Plw + l15 * 128 + ((kcw ^ (l15 & 7)) * 16) + (l4 & 1) * 8) = w;
        }
        rsum += __shfl_xor(rsum, 16);
        rsum += __shfl_xor(rsum, 32);
        lR += rsum;
#pragma unroll
        for (int kstep = 0; kstep < 2; ++kstep) {
            int kcr = kstep * 4 + l4;
            s16x8 pf = *reinterpret_cast<const s16x8*>(Plw + l15 * 128 + ((kcr ^ (l15 & 7)) * 16));
            s16x8 vf0 = *reinterpret_cast<const s16x8*>((char*)Vl + l15 * 128 + ((kcr ^ (l15 & 7)) * 16));
            s16x8 vf1 = *reinterpret_cast<const s16x8*>((char*)Vl + (16 + l15) * 128 + ((kcr ^ (l15 & 7)) * 16));
            o0 = mfma16(pf, vf0, o0);
            o1 = mfma16(pf, vf1, o1);
        }
    }
    float li[4];
#pragma unroll
    for (int r = 0; r < 4; ++r) li[r] = 1.0f / __shfl(lR, l4 * 4 + r);
#pragma unroll
    for (int r = 0; r < 4; ++r) {
        size_t row = ((size_t)ks * Mtok + voxof(blk, q0 + l4 * 4 + r, logs, lbsz)) * 256 + h * 32;
        Opart[row + l15] = f2b(o0[r] * li[r]);
        Opart[row + 16 + l15] = f2b(o1[r] * li[r]);
    }
    if (l4 == 0) ML[((size_t)ks * Mtok + qvox) * 8 + h] = lR;
}

// Fused intra z0+z1 attention, flat 1D grid of 4096 WGs.
// plane0 (z=0): bid<2048: 64 xb x 4 ks x (1 blk x 8 h) = 2048
// plane1 (z=1): bid>=2048: 8 xb x 4 ks x (8 blk x 8 h) = 2048
__global__ __launch_bounds__(256) void attn_fused01_k(
    const unsigned short* __restrict__ QKVA2, const unsigned short* __restrict__ VtgA,
    unsigned short* __restrict__ OpartI, float* __restrict__ MLbuf) {
    __shared__ unsigned short Kl[2048];
    __shared__ unsigned short Vl[2048];
    __shared__ unsigned short Pl[4096];
    int bid = blockIdx.x;
    int plane, xb, ks, zz, L, logs, lbsz;
    if (bid < 2048) {
        plane = 0; xb = bid & 63; ks = (bid >> 6) & 3; zz = bid >> 8;
        L = 4096; logs = 0; lbsz = 4;
    } else {
        int b2 = bid - 2048;
        plane = 1; xb = b2 & 7; ks = (b2 >> 3) & 3; zz = b2 >> 5;
        L = 512; logs = 1; lbsz = 3;
    }
    const int blk = zz >> 3, h = zz & 7;
    const int wave = threadIdx.x >> 6;
    const int q0 = xb * 64 + wave * 16;
    attn_core<0>(QKVA2 + (size_t)plane * 3145728, VtgA + (size_t)plane * 1048576,
                 OpartI + (size_t)plane * 4194304, MLbuf + (size_t)plane * 131072,
                 L, 4096, logs, lbsz, blk, h, 4, ks, q0, Kl, Vl, Pl);
}

// Generic MFMA attention: grid (L/64, KS, nblk*8). KS==1 -> Opart IS final O.
template <int VST>
__global__ __launch_bounds__(256) void attn_mfma2_k(
    const unsigned short* __restrict__ QKV, const unsigned short* __restrict__ Vtg,
    unsigned short* __restrict__ Opart, float* __restrict__ ML,
    int L, int Mtok, int logs, int lbsz) {
    __shared__ unsigned short Kl[2048];
    __shared__ unsigned short Vl[2048];
    __shared__ unsigned short Pl[4096];
    const int blk = blockIdx.z >> 3, h = blockIdx.z & 7;
    const int wave = threadIdx.x >> 6;
    const int q0 = blockIdx.x * 64 + wave * 16;
    attn_core<VST>(QKV, Vtg, Opart, ML, L, Mtok, logs, lbsz,
                   blk, h, gridDim.y, blockIdx.y, q0, Kl, Vl, Pl);
}

// combine: O = sum_ks l*o_norm / sum_ks l
__global__ __launch_bounds__(256) void attn_combine_k(
    const unsigned short* __restrict__ Opart, const float* __restrict__ ML,
    unsigned short* __restrict__ O, int TotTok, int KS,
    long zOp, long zML, long zO) {
    int z = blockIdx.y, row = blockIdx.x, c = threadIdx.x, h = c >> 5;
    Opart += (size_t)z * zOp;
    ML += (size_t)z * zML;
    O += (size_t)z * zO;
    float osum = 0.f, lsum = 0.f;
    for (int ks = 0; ks < KS; ++ks) {
        float l = ML[((size_t)ks * TotTok + row) * 8 + h];
        lsum += l;
        osum += l * b2f(Opart[((size_t)ks * TotTok + row) * 256 + c]);
    }
    O[(size_t)row * 256 + c] = f2b(osum / lsum);
}

// ---------------------------------------------------------------------------
// fp32 fixed-m attention, intra split z=3 only (L=8). grid (1, 4096).
// Q pre-scaled -> p = exp2(S).
// ---------------------------------------------------------------------------
__global__ __launch_bounds__(256) void attn_f32z3_k(const unsigned short* __restrict__ QKV,
                                                    unsigned short* __restrict__ O) {
    const int y = blockIdx.y;
    const int blk = y >> 3, h = y & 7;
    const int L = 8, logs = 3, lbsz = 1;
    const int tid = threadIdx.x, r = tid >> 3, li = tid & 7;
    const int qr = r;
    const int qrc = (qr < L) ? qr : 0;
    const int qvox = voxof(blk, qrc, logs, lbsz);

    float q[32];
    {
        const unsigned short* qp = QKV + (size_t)qvox * 768 + h * 32;
#pragma unroll
        for (int d8 = 0; d8 < 4; ++d8) {
            s16x8 v = *reinterpret_cast<const s16x8*>(qp + d8 * 8);
#pragma unroll
            for (int e = 0; e < 8; ++e) q[d8 * 8 + e] = b2f((unsigned short)v[e]);
        }
    }
    float l = 0.f;
    float o[32];
#pragma unroll
    for (int d = 0; d < 32; ++d) o[d] = 0.f;

    __shared__ float Kl[32][36];
    __shared__ float Vl[32][36];
    const int krow = tid >> 3, kd = (tid & 7) * 4;
    float4 kv = make_float4(0.f, 0.f, 0.f, 0.f);
    float4 vv = make_float4(0.f, 0.f, 0.f, 0.f);
    if (krow < L) {
        int kvox = voxof(blk, krow, logs, lbsz);
        s16x4 k4 = *reinterpret_cast<const s16x4*>(QKV + (size_t)kvox * 768 + 256 + h * 32 + kd);
        s16x4 v4 = *reinterpret_cast<const s16x4*>(QKV + (size_t)kvox * 768 + 512 + h * 32 + kd);
        kv = make_float4(b2f((unsigned short)k4[0]), b2f((unsigned short)k4[1]),
                         b2f((unsigned short)k4[2]), b2f((unsigned short)k4[3]));
        vv = make_float4(b2f((unsigned short)v4[0]), b2f((unsigned short)v4[1]),
                         b2f((unsigned short)v4[2]), b2f((unsigned short)v4[3]));
    }
    __syncthreads();
    Kl[krow][kd + 0] = kv.x; Kl[krow][kd + 1] = kv.y;
    Kl[krow][kd + 2] = kv.z; Kl[krow][kd + 3] = kv.w;
    Vl[krow][kd + 0] = vv.x; Vl[krow][kd + 1] = vv.y;
    Vl[krow][kd + 2] = vv.z; Vl[krow][kd + 3] = vv.w;
    __syncthreads();
#pragma unroll
    for (int j = 0; j < 4; ++j) {
        int kk = j * 8 + li;
        float acc = 0.f;
#pragma unroll
        for (int d4 = 0; d4 < 8; ++d4) {
            float4 k4 = *reinterpret_cast<const float4*>(&Kl[kk][d4 * 4]);
            acc += q[d4 * 4 + 0] * k4.x + q[d4 * 4 + 1] * k4.y +
                   q[d4 * 4 + 2] * k4.z + q[d4 * 4 + 3] * k4.w;
        }
        float p = (kk < L) ? exp2f(acc) : 0.f;
        l += p;
#pragma unroll
        for (int d4 = 0; d4 < 8; ++d4) {
            float4 v4 = *reinterpret_cast<const float4*>(&Vl[kk][d4 * 4]);
            o[d4 * 4 + 0] += p * v4.x; o[d4 * 4 + 1] += p * v4.y;
            o[d4 * 4 + 2] += p * v4.z; o[d4 * 4 + 3] += p * v4.w;
        }
    }
#pragma unroll
    for (int d = 0; d < 32; ++d) {
        o[d] += __shfl_xor(o[d], 1);
        o[d] += __shfl_xor(o[d], 2);
        o[d] += __shfl_xor(o[d], 4);
    }
    l += __shfl_xor(l, 1);
    l += __shfl_xor(l, 2);
    l += __shfl_xor(l, 4);
    if (qr < L) {
        float inv = 1.0f / l;
        size_t orow = (size_t)qvox * 256 + h * 32;
#pragma unroll
        for (int qd = 0; qd < 4; ++qd) O[orow + li * 4 + qd] = f2b(o[li * 4 + qd] * inv);
    }
}

// ---------------------------------------------------------------------------
// fp32 fixed-m inter attention, z in {0,1,2} (L={1,8,64}), identity map.
// Q pre-scaled -> p = exp2(S). grid (2, 24): y -> z = y>>3, h = y&7
// ---------------------------------------------------------------------------
__global__ __launch_bounds__(256) void attn_f32b_k(const unsigned short* __restrict__ RQKV,
                                                   unsigned short* __restrict__ RO) {
    const int y = blockIdx.y;
    const int z = y >> 3, h = y & 7;
    const int Lz[3] = {1, 8, 64};
    const int goffc[3] = {0, 1, 9};
    const int L = Lz[z];
    const unsigned short* base = RQKV + (size_t)goffc[z] * 768;
    unsigned short* O = RO + (size_t)goffc[z] * 256;
    const int tid = threadIdx.x;
    const int r = tid >> 3, li = tid & 7;
    const int qr = blockIdx.x * 32 + r;
    const int qrc = (qr < L) ? qr : 0;

    float q[32];
    {
        const unsigned short* qp = base + (size_t)qrc * 768 + h * 32;
#pragma unroll
        for (int d8 = 0; d8 < 4; ++d8) {
            s16x8 v = *reinterpret_cast<const s16x8*>(qp + d8 * 8);
#pragma unroll
            for (int e = 0; e < 8; ++e) q[d8 * 8 + e] = b2f((unsigned short)v[e]);
        }
    }
    float l = 0.f;
    float o[32];
#pragma unroll
    for (int d = 0; d < 32; ++d) o[d] = 0.f;

    __shared__ float Kl[32][36];
    __shared__ float Vl[32][36];
    const int krow = tid >> 3, kd = (tid & 7) * 4;
    const int nt = (L + 31) / 32;
    for (int kt = 0; kt < nt; ++kt) {
        int key = kt * 32 + krow;
        float4 kv = make_float4(0.f, 0.f, 0.f, 0.f);
        float4 vv = make_float4(0.f, 0.f, 0.f, 0.f);
        if (key < L) {
            s16x4 k4 = *reinterpret_cast<const s16x4*>(base + (size_t)key * 768 + 256 + h * 32 + kd);
            s16x4 v4 = *reinterpret_cast<const s16x4*>(base + (size_t)key * 768 + 512 + h * 32 + kd);
            kv = make_float4(b2f((unsigned short)k4[0]), b2f((unsigned short)k4[1]),
                             b2f((unsigned short)k4[2]), b2f((unsigned short)k4[3]));
            vv = make_float4(b2f((unsigned short)v4[0]), b2f((unsigned short)v4[1]),
                             b2f((unsigned short)v4[2]), b2f((unsigned short)v4[3]));
        }
        __syncthreads();
        Kl[krow][kd + 0] = kv.x; Kl[krow][kd + 1] = kv.y;
        Kl[krow][kd + 2] = kv.z; Kl[krow][kd + 3] = kv.w;
        Vl[krow][kd + 0] = vv.x; Vl[krow][kd + 1] = vv.y;
        Vl[krow][kd + 2] = vv.z; Vl[krow][kd + 3] = vv.w;
        __syncthreads();
#pragma unroll
        for (int j = 0; j < 4; ++j) {
            int kk = j * 8 + li;
            float acc = 0.f;
#pragma unroll
            for (int d4 = 0; d4 < 8; ++d4) {
                float4 k4 = *reinterpret_cast<const float4*>(&Kl[kk][d4 * 4]);
                acc += q[d4 * 4 + 0] * k4.x + q[d4 * 4 + 1] * k4.y +
                       q[d4 * 4 + 2] * k4.z + q[d4 * 4 + 3] * k4.w;
            }
            float p = (kt * 32 + kk < L) ? exp2f(acc) : 0.f;
            l += p;
#pragma unroll
            for (int d4 = 0; d4 < 8; ++d4) {
                float4 v4 = *reinterpret_cast<const float4*>(&Vl[kk][d4 * 4]);
                o[d4 * 4 + 0] += p * v4.x; o[d4 * 4 + 1] += p * v4.y;
                o[d4 * 4 + 2] += p * v4.z; o[d4 * 4 + 3] += p * v4.w;
            }
        }
    }
#pragma unroll
    for (int d = 0; d < 32; ++d) {
        o[d] += __shfl_xor(o[d], 1);
        o[d] += __shfl_xor(o[d], 2);
        o[d] += __shfl_xor(o[d], 4);
    }
    l += __shfl_xor(l, 1);
    l += __shfl_xor(l, 2);
    l += __shfl_xor(l, 4);
    if (qr < L) {
        float inv = 1.0f / l;
        size_t orow = (size_t)qr * 256 + h * 32;
#pragma unroll
        for (int qd = 0; qd < 4; ++qd) O[orow + li * 4 + qd] = f2b(o[li * 4 + qd] * inv);
    }
}

// ---------------------------------------------------------------------------
// intra residual+LN, batched: grid 4*4096; T1 bf16 in, T bf16 out
// ---------------------------------------------------------------------------
__global__ __launch_bounds__(256) void add_ln_b_k(const float* __restrict__ X,
                                                  const unsigned short* __restrict__ T1b,
                                                  const float* __restrict__ g,
                                                  const float* __restrict__ b,
                                                  unsigned short* __restrict__ Tb) {
    int row = blockIdx.x & 4095, z = blockIdx.x >> 12, t = threadIdx.x;
    float v = X[row * 256 + t] + b2f(T1b[(size_t)z * 1048576 + row * 256 + t]);
    float s1 = v, s2 = v * v;
#pragma unroll
    for (int mask = 1; mask < 64; mask <<= 1) {
        s1 += __shfl_xor(s1, mask);
        s2 += __shfl_xor(s2, mask);
    }
    __shared__ float w1[4], w2[4];
    int wv = t >> 6, ln = t & 63;
    if (ln == 0) { w1[wv] = s1; w2[wv] = s2; }
    __syncthreads();
    float tot1 = w1[0] + w1[1] + w1[2] + w1[3];
    float tot2 = w2[0] + w2[1] + w2[2] + w2[3];
    float mean = tot1 * (1.0f / 256.0f);
    float var = tot2 * (1.0f / 256.0f) - mean * mean;
    float rstd = rsqrtf(var + 1e-5f);
    Tb[(size_t)z * 1048576 + row * 256 + t] =
        f2b((v - mean) * rstd * g[z * 256 + t] + b[z * 256 + t]);
}

// batched inter residual+LN over all 585 rows
__global__ __launch_bounds__(256) void add_ln_i_k(const float* __restrict__ Rb_all,
                                                  const float* __restrict__ R1_all,
                                                  const float* __restrict__ g,
                                                  const float* __restrict__ b,
                                                  float* __restrict__ RLN_all) {
    int row = blockIdx.x, t = threadIdx.x;
    int z = (row == 0) ? 0 : (row < 9 ? 1 : (row < 73 ? 2 : 3));
    float v = Rb_all[row * 256 + t] + R1_all[row * 256 + t];
    float s1 = v, s2 = v * v;
#pragma unroll
    for (int mask = 1; mask < 64; mask <<= 1) {
        s1 += __shfl_xor(s1, mask);
        s2 += __shfl_xor(s2, mask);
    }
    __shared__ float w1[4], w2[4];
    int wv = t >> 6, ln = t & 63;
    if (ln == 0) { w1[wv] = s1; w2[wv] = s2; }
    __syncthreads();
    float tot1 = w1[0] + w1[1] + w1[2] + w1[3];
    float tot2 = w2[0] + w2[1] + w2[2] + w2[3];
    float mean = tot1 * (1.0f / 256.0f);
    float var = tot2 * (1.0f / 256.0f) - mean * mean;
    float rstd = rsqrtf(var + 1e-5f);
    RLN_all[row * 256 + t] = (v - mean) * rstd * g[z * 256 + t] + b[z * 256 + t];
}

// batched block means from bf16 T, bounded contention; grid 896
__global__ __launch_bounds__(256) void block_mean_b_k(const unsigned short* __restrict__ Tb_all,
                                                      float* __restrict__ Rb_all) {
    int bx = blockIdx.x, c = threadIdx.x;
    int z, blk, ch, rpc;
    float inv_bs;
    if (bx < 128)      { z = 0; blk = 0;               ch = bx;              rpc = 32; inv_bs = 1.0f / 4096.0f; }
    else if (bx < 256) { int l = bx - 128; z = 1; blk = l >> 4; ch = l & 15; rpc = 32; inv_bs = 1.0f / 512.0f; }
    else if (bx < 384) { int l = bx - 256; z = 2; blk = l >> 1; ch = l & 1;  rpc = 32; inv_bs = 1.0f / 64.0f; }
    else               { int l = bx - 384; z = 3; blk = l;      ch = 0;      rpc = 8;  inv_bs = 1.0f / 8.0f; }
    const int goffc[4] = {0, 1, 9, 73};
    const int logs = z, lbsz = 4 - z;
    const unsigned short* T = Tb_all + (size_t)z * 1048576;
    float* R = Rb_all + (size_t)(goffc[z] + blk) * 256;
    int p0 = ch * rpc;
    float sum = 0.f;
    for (int p = p0; p < p0 + rpc; ++p)
        sum += b2f(T[(size_t)voxof(blk, p, logs, lbsz) * 256 + c]);
    atomicAdd(&R[c], sum * inv_bs);
}

// BN stats over Yt [4096 vox][256 ch]
__global__ __launch_bounds__(256) void bn_stats_k(const float* __restrict__ Yt,
                                                  float* __restrict__ MV) {
    int b0 = blockIdx.x * 16, c = threadIdx.x;
    float s1 = 0.f, s2 = 0.f;
#pragma unroll
    for (int j = 0; j < 16; ++j) {
        float v = Yt[(size_t)(b0 + j) * 256 + c];
        s1 += v; s2 += v * v;
    }
    atomicAdd(&MV[c], s1);
    atomicAdd(&MV[256 + c], s2);
}

__global__ __launch_bounds__(256) void bn_apply_k(const float* __restrict__ Yt,
                                                  const float* __restrict__ MV,
                                                  const float* __restrict__ g,
                                                  const float* __restrict__ b,
                                                  float* __restrict__ outp) {
    int c = blockIdx.x, t = threadIdx.x;
    float mean = MV[c] * (1.0f / 4096.0f);
    float var = MV[256 + c] * (1.0f / 4096.0f) - mean * mean;
    float rstd = rsqrtf(var + 1e-5f);
    float gg = g[c] * rstd, bb = b[c] - mean * gg;
    for (int it = 0; it < 16; ++it) {
        int v = it * 256 + t;
        float y = Yt[(size_t)v * 256 + c];
        float rr = y * gg + bb;
        outp[(size_t)c * 4096 + v] = rr > 0.f ? rr : 0.f;
    }
}

// ---------------------------------------------------------------------------
extern "C" void kernel_launch(void* const* d_in, const int* in_sizes, int n_in,
                              void* d_out, int out_size, void* d_ws, size_t ws_size,
                              hipStream_t stream) {
    (void)in_sizes; (void)n_in; (void)out_size; (void)ws_size;
    const float* x          = (const float*)d_in[0];
    const float* intra_bqkv = (const float*)d_in[2];
    const float* intra_bout = (const float*)d_in[4];
    const float* intra_ln_g = (const float*)d_in[5];
    const float* intra_ln_b = (const float*)d_in[6];
    const float* inter_bqkv = (const float*)d_in[8];
    const float* inter_bout = (const float*)d_in[10];
    const float* inter_ln_g = (const float*)d_in[11];
    const float* inter_ln_b = (const float*)d_in[12];
    const float* ffn_b1     = (const float*)d_in[14];
    const float* ffn_b2     = (const float*)d_in[16];
    const float* bn_g       = (const float*)d_in[18];
    const float* bn_b       = (const float*)d_in[19];
    float* out = (float*)d_out;

    float* ws = (float*)d_ws;
    unsigned short* OUTt  = (unsigned short*)ws;                  // 2,097,152 f
    float* Xt             = ws + 2097152;                         // 1,048,576
    unsigned short* Xtb   = (unsigned short*)(ws + 3145728);      // 524,288
    unsigned short* QKVA2 = (unsigned short*)(ws + 3670016);      // [2][4096][768]
    unsigned short* ObfA  = (unsigned short*)(ws + 6815744);      // [4][4096][256]
    unsigned short* T1A   = (unsigned short*)(ws + 8912896);      // [4][4096][256] bf16
    unsigned short* TAb   = (unsigned short*)(ws + 11010048);     // [4][4096][256] bf16
    float* Rb_all         = ws + 13107200;                        // 149,760
    unsigned short* RQKVa = (unsigned short*)(ws + 13256960);     // 449,280 sh
    unsigned short* RObA  = (unsigned short*)(ws + 13481600);     // 149,760 sh
    float* R1A            = ws + 13556480;                        // 149,760
    float* RLN_all        = ws + 13706240;                        // 149,760
    unsigned short* WB    = (unsigned short*)(ws + 13856000);     // 3,407,872 sh
    unsigned short* VtgA  = (unsigned short*)(ws + 15559936);     // [2][256][4096]
    unsigned short* Vtgr  = (unsigned short*)(ws + 16608512);     // 131,072 sh
    float* MLbuf          = ws + 16674048;                        // 262,144 f
    // lifetime aliases:
    unsigned short* OpartI = T1A;                 // [2][4][4096][256] bf16 over T1A+TAb
    unsigned short* OpartR = T1A;                 // [8][512][256] bf16 (Phase D)
    unsigned short* HidA   = QKVA2;               // [4][4096][512] bf16 over QKVA2+ObfA
    float* MV              = MLbuf;               // 512 f32 (after attn)
    float* Yt              = Xt;                  // fuse output

    unsigned short* WBq  = WB;
    unsigned short* WBo  = WB + 786432;
    unsigned short* WBiq = WB + 1048576;
    unsigned short* WBio = WB + 1835008;
    unsigned short* WBf1 = WB + 2097152;
    unsigned short* WBf2 = WB + 2621440;
    unsigned short* WBfu = WB + 3145728;

    const long ZC = 1048576;

    prologue_k<<<4499, 256, 0, stream>>>((const float*)d_in[1], (const float*)d_in[3],
                                         (const float*)d_in[7], (const float*)d_in[9],
                                         (const float*)d_in[13], (const float*)d_in[15],
                                         (const float*)d_in[17], WB, x, Xt, Xtb, Rb_all);

    // ---- Phase A: QKV z in {0,1} (batched, V^T, Q pre-scaled) + fused MFMA attn ----
    gemm_k<4, 1, 0, 1, 1, 0, 0, 0, 1><<<dim3(12, 32, 2), 256, 0, stream>>>(
        Xtb, WBq, intra_bqkv, QKVA2, 4096, 768, 256, 768,
        0, 196608, 768, 3145728, VtgA, 4096, 1048576, TAb, Rb_all, Xt);
    attn_fused01_k<<<4096, 256, 0, stream>>>(QKVA2, VtgA, OpartI, MLbuf);
    attn_combine_k<<<dim3(4096, 2), 256, 0, stream>>>(
        OpartI, MLbuf, ObfA, 4096, 4, 4194304, 131072, 1048576);
    // ---- QKV z in {2,3} (batched, V^T, Q pre-scaled) + MFMA z2 (VST=1) + f32 z3 ----
    gemm_k<4, 1, 0, 1, 1, 0, 0, 0, 1><<<dim3(12, 32, 2), 256, 0, stream>>>(
        Xtb, WBq + 2 * 196608, intra_bqkv + 2 * 768, QKVA2, 4096, 768, 256, 768,
        0, 196608, 768, 3145728, VtgA, 4096, 1048576, TAb, Rb_all, Xt);
    attn_mfma2_k<1><<<dim3(1, 1, 512), 256, 0, stream>>>(
        QKVA2, VtgA, ObfA + 2 * ZC, MLbuf, 64, 4096, 2, 2);
    attn_f32z3_k<<<dim3(1, 4096), 256, 0, stream>>>(QKVA2 + 3145728, ObfA + 3 * ZC);
    // ---- Phase B: batched out-projection -> T1A (bf16), MFR=2 ----
    gemm_k<2, 1, 0, 1, 0, 0, 0, 0, 0><<<dim3(4, 64, 4), 256, 0, stream>>>(
        ObfA, WBo, intra_bout, T1A, 4096, 256, 256, 256,
        ZC, 65536, 256, ZC, nullptr, 0, 0, TAb, Rb_all, Xt);
    // ---- Phase C: batched residual+LN -> TAb; block means -> Rb_all ----
    add_ln_b_k<<<16384, 256, 0, stream>>>(Xt, T1A, intra_ln_g, intra_ln_b, TAb);
    block_mean_b_k<<<896, 256, 0, stream>>>(TAb, Rb_all);
    // ---- Phase D: inter chain (Q pre-scaled in D1) ----
    gemm_k<2, 1, 0, 1, 1, 1, 0, 2, 1><<<dim3(12, 8, 4), 256, 0, stream>>>(
        Rb_all, WBiq, inter_bqkv, RQKVa, 512, 768, 256, 768,
        0, 196608, 768, 0, Vtgr, 512, 0, TAb, Rb_all, Xt);
    attn_mfma2_k<0><<<dim3(8, 8, 8), 256, 0, stream>>>(
        RQKVa + (size_t)73 * 768, Vtgr, OpartR, MLbuf, 512, 512, 0, 4);
    attn_f32b_k<<<dim3(2, 24), 256, 0, stream>>>(RQKVa, RObA);
    attn_combine_k<<<dim3(512, 1), 256, 0, stream>>>(
        OpartR, MLbuf, RObA + (size_t)73 * 256, 512, 8, 0, 0, 0);
    gemm_k<2, 1, 0, 0, 0, 0, 0, 2, 0><<<dim3(4, 8, 4), 256, 0, stream>>>(
        RObA, WBio, inter_bout, R1A, 512, 256, 256, 256,
        0, 65536, 256, 0, nullptr, 0, 0, TAb, Rb_all, Xt);
    add_ln_i_k<<<585, 256, 0, stream>>>(Rb_all, R1A, inter_ln_g, inter_ln_b, RLN_all);
    // ---- Phase E: batched FFN1 (bf16 T + RLN fused A, GELU) -> HidA ----
    gemm_k<4, 1, 1, 1, 0, 3, 0, 1, 0><<<dim3(8, 32, 4), 256, 0, stream>>>(
        TAb, WBf1, ffn_b1, HidA, 4096, 512, 256, 512,
        ZC, 131072, 512, 2097152, nullptr, 0, 0, TAb, RLN_all, Xt);
    // ---- Phase F: batched FFN2 (+T+RLN+X residuals) -> OUTt columns, MFR=2 ----
    gemm_k<2, 1, 0, 1, 0, 0, 1, 1, 0><<<dim3(4, 64, 4), 256, 0, stream>>>(
        HidA, WBf2, ffn_b2, OUTt, 4096, 256, 512, 1024,
        2097152, 131072, 256, 256, nullptr, 0, 0, TAb, RLN_all, Xt);
    // ---- Phase G: fuse conv + BN + ReLU, MFR=2 ----
    gemm_k<2, 0, 0, 0, 0, 0, 0, 0, 0><<<dim3(4, 64, 1), 256, 0, stream>>>(
        OUTt, WBfu, nullptr, Yt, 4096, 256, 1024, 256,
        0, 0, 0, 0, nullptr, 0, 0, TAb, Rb_all, Xt);
    hipMemsetAsync(MV, 0, 512 * sizeof(float), stream);
    bn_stats_k<<<256, 256, 0, stream>>>(Yt, MV);
    bn_apply_k<<<256, 256, 0, stream>>>(Yt, MV, bn_g, bn_b, out);
}

// Round 19
// 252.076 us; speedup vs baseline: 1.0737x; 1.0378x over previous
//
#include <hip/hip_runtime.h>
#include <math.h>

typedef __attribute__((ext_vector_type(8))) short s16x8;
typedef __attribute__((ext_vector_type(4))) short s16x4;
typedef __attribute__((ext_vector_type(4))) float f32x4;

__device__ __forceinline__ float b2f(unsigned short u) {
    union { unsigned u; float f; } x;
    x.u = ((unsigned)u) << 16;
    return x.f;
}
__device__ __forceinline__ unsigned short f2b(float f) {
    union { float f; unsigned u; } x;
    x.f = f;
    unsigned u = x.u;
    return (unsigned short)((u + 0x7FFFu + ((u >> 16) & 1u)) >> 16);
}
__device__ __forceinline__ f32x4 mfma16(s16x8 a, s16x8 b, f32x4 c) {
    return __builtin_amdgcn_mfma_f32_16x16x32_bf16(a, b, c, 0, 0, 0);
}
__device__ __forceinline__ float gelu_exact(float x) {
    return 0.5f * x * (1.0f + erff(x * 0.70710678118654752440f));
}
__device__ __forceinline__ void gload_lds16(const void* g, void* l) {
    __builtin_amdgcn_global_load_lds(
        (const __attribute__((address_space(1))) unsigned int*)g,
        (__attribute__((address_space(3))) unsigned int*)l, 16, 0, 0);
}
// raster voxel of (block, position) for split s=1<<logs, bsz=1<<lbsz
__device__ __forceinline__ int voxof(int blk, int pos, int logs, int lbsz) {
    int bm = (1 << lbsz) - 1, sm = (1 << logs) - 1;
    int ix = pos & bm, iy = (pos >> lbsz) & bm, iz = pos >> (2 * lbsz);
    int gx = blk & sm, gy = (blk >> logs) & sm, gz = blk >> (2 * logs);
    return (((gz << lbsz) + iz) << 8) + (((gy << lbsz) + iy) << 4) + ((gx << lbsz) + ix);
}
__device__ __forceinline__ int blkof(int v, int logs, int lbsz) {
    int gx = (v & 15) >> lbsz, gy = ((v >> 4) & 15) >> lbsz, gz = ((v >> 8) & 15) >> lbsz;
    return (((gz << logs) + gy) << logs) + gx;
}

// ---------------------------------------------------------------------------
// Prologue: weights->bf16 (bx<3328), x transpose (bx<4352), Rb zero (rest)
// ---------------------------------------------------------------------------
__global__ __launch_bounds__(256) void prologue_k(
    const float* w0, const float* w1, const float* w2, const float* w3,
    const float* w4, const float* w5, const float* w6,
    unsigned short* __restrict__ wdst, const float* __restrict__ x,
    float* __restrict__ Xt, unsigned short* __restrict__ Xtb,
    float* __restrict__ Rb) {
    __shared__ float tile[32][33];
    int bx = blockIdx.x;
    if (bx < 3328) {
        int i = (bx * 256 + threadIdx.x) * 4;
        const float* s; int off;
        if (i < 786432)        { s = w0; off = 0; }
        else if (i < 1048576)  { s = w1; off = 786432; }
        else if (i < 1835008)  { s = w2; off = 1048576; }
        else if (i < 2097152)  { s = w3; off = 1835008; }
        else if (i < 2621440)  { s = w4; off = 2097152; }
        else if (i < 3145728)  { s = w5; off = 2621440; }
        else                   { s = w6; off = 3145728; }
        float4 v = *reinterpret_cast<const float4*>(s + (i - off));
        wdst[i + 0] = f2b(v.x); wdst[i + 1] = f2b(v.y);
        wdst[i + 2] = f2b(v.z); wdst[i + 3] = f2b(v.w);
    } else if (bx < 4352) {
        int t = bx - 3328;
        int v0 = (t & 127) * 32, c0 = (t >> 7) * 32;
        int tx = threadIdx.x & 31, ty = threadIdx.x >> 5;
#pragma unroll
        for (int j = 0; j < 32; j += 8)
            tile[ty + j][tx] = x[(size_t)(c0 + ty + j) * 4096 + v0 + tx];
        __syncthreads();
#pragma unroll
        for (int j = 0; j < 32; j += 8) {
            float v = tile[tx][ty + j];
            size_t o = (size_t)(v0 + ty + j) * 256 + c0 + tx;
            Xt[o] = v;
            Xtb[o] = f2b(v);
        }
    } else {
        int idx = ((bx - 4352) * 256 + threadIdx.x) * 4;
        if (idx < 149760) {
            float4 z4 = make_float4(0.f, 0.f, 0.f, 0.f);
            *reinterpret_cast<float4*>(Rb + idx) = z4;
        }
    }
}

// ---------------------------------------------------------------------------
// bf16 MFMA GEMM, BM=32*MFR, BN=64, BK=64, 256 thr (4 waves 2x2), z-batched.
// AF32: 0 = A bf16 gload_lds; 1 = A f32 reg-staged;
//       2 = A f32 + RLN[blk] (ZS=1); 3 = A bf16 + RLN[blk] (ZS=1)
// EPI:  1 = FFN2: v += bf16 T[z] + RLN[goff+blk] + X; write bf16
// VT:   n in [512,768) also to vt[z*zsV + (n-512)*mtot + m]
// ZS:   1 = per-split mode (logs=z); 2 = inter mode (M={1,8,64,512}[z], goff rows)
// QSC:  1 = scale Q columns (n<256) by cscale = log2(e)/sqrt(32)
// ---------------------------------------------------------------------------
template <int MFR, int HASB, int ACT, int OBF, int VT, int AF32, int EPI, int ZS, int QSC>
__global__ __launch_bounds__(256) void gemm_k(
    const void* __restrict__ Aptr, const unsigned short* __restrict__ W,
    const float* __restrict__ bias, void* __restrict__ outp,
    int M, int N, int K, int ldC,
    long zsA, long zsW, long zsB, long zsC,
    unsigned short* __restrict__ vt, int mtot, long zsV,
    const void* __restrict__ Tresv, const float* __restrict__ RLNres,
    const float* __restrict__ Xres) {
    constexpr int BM = 32 * MFR;
    __shared__ unsigned short As[BM * 64];
    __shared__ unsigned short Ws[64 * 64];
    const int z = blockIdx.z;
    const int logs = (ZS == 1) ? z : 0;
    const int lbsz = (ZS == 1) ? (4 - z) : 4;
    const int goffc[4] = {0, 1, 9, 73};
    const int Mzc[4] = {1, 8, 64, 512};
    const int Me = (ZS == 2) ? Mzc[z] : M;
    const int m0 = blockIdx.y * BM, n0 = blockIdx.x * 64;
    if (ZS == 2 && m0 >= Me) return;
    const unsigned short* Ab = (const unsigned short*)Aptr +
        ((AF32 == 0 || AF32 == 3) ? ((size_t)z * zsA + (ZS == 2 ? (size_t)goffc[z] * K : 0)) : 0);
    const float* Af = (const float*)Aptr +
        ((AF32 == 1 || AF32 == 2) ? ((size_t)z * zsA + (ZS == 2 ? (size_t)goffc[z] * K : 0)) : 0);
    W += (size_t)z * zsW;
    const float* biasz = bias + (HASB ? (size_t)z * zsB : 0);
    char* outc = (char*)outp +
        ((size_t)z * zsC + (ZS == 2 ? (size_t)goffc[z] * ldC : 0)) * ((OBF || EPI) ? 2 : 4);
    const float* RLNz = RLNres + (ZS == 1 ? goffc[z] * 256 : 0);
    const unsigned short* Tzb = (const unsigned short*)Tresv + (ZS == 1 ? (size_t)z * 1048576 : 0);

    const int tid = threadIdx.x;
    const int wave = tid >> 6, lane = tid & 63;
    const int l15 = lane & 15, l4 = lane >> 4;
    const int wr = wave >> 1, wc = wave & 1;
    const int srow = lane >> 3;
    const int schunk = (lane & 7) ^ srow;
    f32x4 acc[MFR][2] = {};
    for (int k0 = 0; k0 < K; k0 += 64) {
        s16x8 sreg[MFR];
        if (AF32) {
#pragma unroll
            for (int i = 0; i < MFR; ++i) {
                int ca = wave * MFR + i;
                int gr = m0 + ca * 8 + srow;
                gr = gr < Me ? gr : (Me - 1);
                s16x8 pk;
                if (AF32 == 3) {
                    s16x8 tb = *reinterpret_cast<const s16x8*>(Ab + (size_t)gr * K + k0 + schunk * 8);
                    const float* rl = RLNz + (size_t)blkof(gr, logs, lbsz) * 256 + k0 + schunk * 8;
#pragma unroll
                    for (int e = 0; e < 8; ++e) pk[e] = (short)f2b(b2f((unsigned short)tb[e]) + rl[e]);
                } else {
                    const float* src = Af + (size_t)gr * K + k0 + schunk * 8;
                    float4 u = *reinterpret_cast<const float4*>(src);
                    float4 w2 = *reinterpret_cast<const float4*>(src + 4);
                    if (AF32 == 2) {
                        const float* rl = RLNz + (size_t)blkof(gr, logs, lbsz) * 256 + k0 + schunk * 8;
                        float4 a = *reinterpret_cast<const float4*>(rl);
                        float4 b = *reinterpret_cast<const float4*>(rl + 4);
                        u.x += a.x; u.y += a.y; u.z += a.z; u.w += a.w;
                        w2.x += b.x; w2.y += b.y; w2.z += b.z; w2.w += b.w;
                    }
                    pk[0] = (short)f2b(u.x); pk[1] = (short)f2b(u.y);
                    pk[2] = (short)f2b(u.z); pk[3] = (short)f2b(u.w);
                    pk[4] = (short)f2b(w2.x); pk[5] = (short)f2b(w2.y);
                    pk[6] = (short)f2b(w2.z); pk[7] = (short)f2b(w2.w);
                }
                sreg[i] = pk;
            }
        }
        __syncthreads();
        if (AF32) {
#pragma unroll
            for (int i = 0; i < MFR; ++i) {
                int ca = wave * MFR + i;
                *reinterpret_cast<s16x8*>((char*)As + ca * 1024 + lane * 16) = sreg[i];
            }
        } else {
#pragma unroll
            for (int i = 0; i < MFR; ++i) {
                int ca = wave * MFR + i;
                int gr = m0 + ca * 8 + srow;
                gr = gr < Me ? gr : (Me - 1);
                gload_lds16(Ab + (size_t)gr * K + k0 + schunk * 8, (char*)As + ca * 1024);
            }
        }
#pragma unroll
        for (int i = 0; i < 2; ++i) {
            int cb = wave * 2 + i;
            int gr = n0 + cb * 8 + srow;
            gload_lds16(W + (size_t)gr * K + k0 + schunk * 8, (char*)Ws + cb * 1024);
        }
        asm volatile("s_waitcnt vmcnt(0)" ::: "memory");
        __syncthreads();
#pragma unroll
        for (int ks = 0; ks < 2; ++ks) {
            s16x8 af[MFR], bf[2];
#pragma unroll
            for (int mf = 0; mf < MFR; ++mf) {
                int row = wr * (MFR * 16) + mf * 16 + l15;
                int ch = (ks * 4 + l4) ^ (row & 7);
                af[mf] = *reinterpret_cast<const s16x8*>((char*)As + row * 128 + ch * 16);
            }
#pragma unroll
            for (int nf = 0; nf < 2; ++nf) {
                int row = wc * 32 + nf * 16 + l15;
                int ch = (ks * 4 + l4) ^ (row & 7);
                bf[nf] = *reinterpret_cast<const s16x8*>((char*)Ws + row * 128 + ch * 16);
            }
#pragma unroll
            for (int mf = 0; mf < MFR; ++mf)
#pragma unroll
                for (int nf = 0; nf < 2; ++nf)
                    acc[mf][nf] = mfma16(af[mf], bf[nf], acc[mf][nf]);
        }
    }
#pragma unroll
    for (int nf = 0; nf < 2; ++nf) {
        int n = n0 + wc * 32 + nf * 16 + l15;
        float bv = HASB ? biasz[n] : 0.0f;
#pragma unroll
        for (int mf = 0; mf < MFR; ++mf) {
            float vr[4];
#pragma unroll
            for (int r = 0; r < 4; ++r) {
                int m = m0 + wr * (MFR * 16) + mf * 16 + l4 * 4 + r;
                float v = acc[mf][nf][r] + bv;
                if (ACT == 1) v = gelu_exact(v);
                if (QSC) { if (n < 256) v *= (0.17677669529663687f * 1.44269504088896f); }
                vr[r] = v;
                if (m < Me) {
                    size_t co = (size_t)m * ldC + n;
                    if (EPI == 1) {
                        v += b2f(Tzb[(size_t)m * 256 + n]) +
                             RLNz[(size_t)blkof(m, logs, lbsz) * 256 + n] +
                             Xres[(size_t)m * 256 + n];
                        ((unsigned short*)outc)[co] = f2b(v);
                    } else if (OBF) {
                        ((unsigned short*)outc)[co] = f2b(v);
                    } else {
                        ((float*)outc)[co] = v;
                    }
                }
            }
            if (VT) {
                if ((ZS != 2 || z == 3) && n >= 512) {
                    s16x4 pk;
#pragma unroll
                    for (int r = 0; r < 4; ++r) pk[r] = (short)f2b(vr[r]);
                    int mb = m0 + wr * (MFR * 16) + mf * 16 + l4 * 4;
                    *reinterpret_cast<s16x4*>(vt + (size_t)z * zsV + (size_t)(n - 512) * mtot + mb) = pk;
                }
            }
        }
    }
}

// ---------------------------------------------------------------------------
// Shared MFMA flash-attention tile body (fixed-m softmax, Q pre-scaled so
// P = exp2(S) directly). VST=0: V^T via gload_lds16 (needs 8 consecutive
// positions == 8 consecutive voxels). VST=1: reg-staged 2x4-voxel loads
// (required for lbsz==2, z=2 intra).
// ---------------------------------------------------------------------------
template <int VST>
__device__ __forceinline__ void attn_core(
    const unsigned short* QKV, const unsigned short* Vtg,
    unsigned short* Opart, float* ML,
    int L, int Mtok, int logs, int lbsz,
    int blk, int h, int KS, int ks, int q0,
    unsigned short* Kl, unsigned short* Vl, unsigned short* Pl) {
    const int wave = threadIdx.x >> 6, lane = threadIdx.x & 63;
    const int l15 = lane & 15, l4 = lane >> 4;
    char* Plw = (char*)Pl + wave * 2048;

    const int qvox = voxof(blk, q0 + l15, logs, lbsz);
    s16x8 qf = *reinterpret_cast<const s16x8*>(QKV + (size_t)qvox * 768 + h * 32 + l4 * 8);

    f32x4 o0 = {}, o1 = {};
    float lR = 0.f;

    const int krow = threadIdx.x >> 2, kch = threadIdx.x & 3;
    const int kcol = (kch ^ (krow & 3)) * 8;
    const int vd = threadIdx.x >> 3, vc = threadIdx.x & 7;
    const int vrun = (vc ^ (vd & 7)) * 8;

    const int nt = L / (64 * KS);
    const int kb0 = ks * (L / KS);
    const int vstep = (nt > 1)
        ? (voxof(blk, kb0 + 64, logs, lbsz) - voxof(blk, kb0, logs, lbsz)) : 0;
    const unsigned short* ksrc =
        QKV + (size_t)voxof(blk, kb0 + krow, logs, lbsz) * 768 + 256 + h * 32 + kcol;
    const unsigned short* vsrc =
        Vtg + (size_t)(h * 32 + vd) * Mtok + voxof(blk, kb0 + vrun, logs, lbsz);
    const unsigned short* vsrc2 =
        Vtg + (size_t)(h * 32 + vd) * Mtok + voxof(blk, kb0 + vrun + 4, logs, lbsz);
    const size_t kadv = (size_t)vstep * 768;
    char* kdst = (char*)Kl + wave * 1024;
    char* vdst = (char*)Vl + wave * 1024;

    for (int it = 0; it < nt; ++it) {
        __syncthreads();
        gload_lds16(ksrc, kdst);
        if (VST == 0) {
            gload_lds16(vsrc, vdst);
        } else {
            s16x4 lo = *reinterpret_cast<const s16x4*>(vsrc);
            s16x4 hi = *reinterpret_cast<const s16x4*>(vsrc2);
            s16x8 vv;
            vv[0] = lo[0]; vv[1] = lo[1]; vv[2] = lo[2]; vv[3] = lo[3];
            vv[4] = hi[0]; vv[5] = hi[1]; vv[6] = hi[2]; vv[7] = hi[3];
            *reinterpret_cast<s16x8*>((char*)Vl + threadIdx.x * 16) = vv;
        }
        ksrc += kadv; vsrc += vstep; vsrc2 += vstep;
        asm volatile("s_waitcnt vmcnt(0)" ::: "memory");
        __syncthreads();

        f32x4 st[4];
        const f32x4 zz = {0.f, 0.f, 0.f, 0.f};
#pragma unroll
        for (int t4 = 0; t4 < 4; ++t4) {
            s16x8 kf = *reinterpret_cast<const s16x8*>(
                (char*)Kl + (t4 * 16 + l15) * 64 + ((l4 ^ (l15 & 3)) << 4));
            st[t4] = mfma16(kf, qf, zz);
        }
        float rsum = 0.f;
#pragma unroll
        for (int t4 = 0; t4 < 4; ++t4) {
            float p0 = exp2f(st[t4][0]);
            float p1 = exp2f(st[t4][1]);
            float p2 = exp2f(st[t4][2]);
            float p3 = exp2f(st[t4][3]);
            rsum += (p0 + p1) + (p2 + p3);
            unsigned d0, d1;
            asm("v_cvt_pk_bf16_f32 %0, %1, %2" : "=v"(d0) : "v"(p0), "v"(p1));
            asm("v_cvt_pk_bf16_f32 %0, %1, %2" : "=v"(d1) : "v"(p2), "v"(p3));
            int kcw = t4 * 2 + (l4 >> 1);
            uint2 w; w.x = d0; w.y = d1;
            *reinterpret_cast<uint2*>(Plw + l15 * 128 + ((kcw ^ (l15 & 7)) * 16) + (l4 & 1) * 8) = w;
        }
        rsum += __shfl_xor(rsum, 16);
        rsum += __shfl_xor(rsum, 32);
        lR += rsum;
#pragma unroll
        for (int kstep = 0; kstep < 2; ++kstep) {
            int kcr = kstep * 4 + l4;
            s16x8 pf = *reinterpret_cast<const s16x8*>(Plw + l15 * 128 + ((kcr ^ (l15 & 7)) * 16));
            s16x8 vf0 = *reinterpret_cast<const s16x8*>((char*)Vl + l15 * 128 + ((kcr ^ (l15 & 7)) * 16));
            s16x8 vf1 = *reinterpret_cast<const s16x8*>((char*)Vl + (16 + l15) * 128 + ((kcr ^ (l15 & 7)) * 16));
            o0 = mfma16(pf, vf0, o0);
            o1 = mfma16(pf, vf1, o1);
        }
    }
    float li[4];
#pragma unroll
    for (int r = 0; r < 4; ++r) li[r] = 1.0f / __shfl(lR, l4 * 4 + r);
#pragma unroll
    for (int r = 0; r < 4; ++r) {
        size_t row = ((size_t)ks * Mtok + voxof(blk, q0 + l4 * 4 + r, logs, lbsz)) * 256 + h * 32;
        Opart[row + l15] = f2b(o0[r] * li[r]);
        Opart[row + 16 + l15] = f2b(o1[r] * li[r]);
    }
    if (l4 == 0) ML[((size_t)ks * Mtok + qvox) * 8 + h] = lR;
}

// Fused intra z0+z1 attention, flat 1D grid of 4096 WGs.
// plane0 (z=0): bid<2048: 64 xb x 4 ks x (1 blk x 8 h) = 2048
// plane1 (z=1): bid>=2048: 8 xb x 4 ks x (8 blk x 8 h) = 2048
__global__ __launch_bounds__(256) void attn_fused01_k(
    const unsigned short* __restrict__ QKVA2, const unsigned short* __restrict__ VtgA,
    unsigned short* __restrict__ OpartI, float* __restrict__ MLbuf) {
    __shared__ unsigned short Kl[2048];
    __shared__ unsigned short Vl[2048];
    __shared__ unsigned short Pl[4096];
    int bid = blockIdx.x;
    int plane, xb, ks, zz, L, logs, lbsz;
    if (bid < 2048) {
        plane = 0; xb = bid & 63; ks = (bid >> 6) & 3; zz = bid >> 8;
        L = 4096; logs = 0; lbsz = 4;
    } else {
        int b2 = bid - 2048;
        plane = 1; xb = b2 & 7; ks = (b2 >> 3) & 3; zz = b2 >> 5;
        L = 512; logs = 1; lbsz = 3;
    }
    const int blk = zz >> 3, h = zz & 7;
    const int wave = threadIdx.x >> 6;
    const int q0 = xb * 64 + wave * 16;
    attn_core<0>(QKVA2 + (size_t)plane * 3145728, VtgA + (size_t)plane * 1048576,
                 OpartI + (size_t)plane * 4194304, MLbuf + (size_t)plane * 131072,
                 L, 4096, logs, lbsz, blk, h, 4, ks, q0, Kl, Vl, Pl);
}

// ---------------------------------------------------------------------------
// Fused tail: combine01 (bid<8192) + z2 MFMA KS=1 (bid<8704) + z3 f32 (rest).
// Deps: fused01 done (combine) and QKV23 done (z2/z3) -- satisfied by stream
// order prologue->QKV01->fused01->QKV23->this.
// ---------------------------------------------------------------------------
__global__ __launch_bounds__(256) void attn_tail_k(
    const unsigned short* __restrict__ OpartI, const float* __restrict__ MLbuf,
    unsigned short* __restrict__ ObfA,
    const unsigned short* __restrict__ QKVA2, const unsigned short* __restrict__ VtgA,
    float* __restrict__ MLscr) {
    int bid = blockIdx.x;
    const int tid = threadIdx.x;
    if (bid < 8192) {
        int z = bid >> 12, row = bid & 4095, c = tid, h = c >> 5;
        const unsigned short* Op = OpartI + (size_t)z * 4194304;
        const float* ML = MLbuf + (size_t)z * 131072;
        unsigned short* O = ObfA + (size_t)z * 1048576;
        float osum = 0.f, lsum = 0.f;
        for (int ks = 0; ks < 4; ++ks) {
            float l = ML[((size_t)ks * 4096 + row) * 8 + h];
            lsum += l;
            osum += l * b2f(Op[((size_t)ks * 4096 + row) * 256 + c]);
        }
        O[(size_t)row * 256 + c] = f2b(osum / lsum);
    } else if (bid < 8704) {
        __shared__ unsigned short Kl[2048];
        __shared__ unsigned short Vl[2048];
        __shared__ unsigned short Pl[4096];
        int zz = bid - 8192;
        const int blk = zz >> 3, h = zz & 7;
        const int wave = tid >> 6;
        attn_core<1>(QKVA2, VtgA, ObfA + (size_t)2 * 1048576, MLscr,
                     64, 4096, 2, 2, blk, h, 1, 0, wave * 16, Kl, Vl, Pl);
    } else {
        // z3 f32 fixed-m attention (L=8), Q pre-scaled -> p = exp2(S)
        __shared__ float Kl3[32][36];
        __shared__ float Vl3[32][36];
        const unsigned short* QKV = QKVA2 + 3145728;
        unsigned short* O = ObfA + (size_t)3 * 1048576;
        int y = bid - 8704;
        const int blk = y >> 3, h = y & 7;
        const int L = 8, logs = 3, lbsz = 1;
        const int r = tid >> 3, li = tid & 7;
        const int qr = r;
        const int qrc = (qr < L) ? qr : 0;
        const int qvox = voxof(blk, qrc, logs, lbsz);
        float q[32];
        {
            const unsigned short* qp = QKV + (size_t)qvox * 768 + h * 32;
#pragma unroll
            for (int d8 = 0; d8 < 4; ++d8) {
                s16x8 v = *reinterpret_cast<const s16x8*>(qp + d8 * 8);
#pragma unroll
                for (int e = 0; e < 8; ++e) q[d8 * 8 + e] = b2f((unsigned short)v[e]);
            }
        }
        float l = 0.f;
        float o[32];
#pragma unroll
        for (int d = 0; d < 32; ++d) o[d] = 0.f;
        const int krow = tid >> 3, kd = (tid & 7) * 4;
        float4 kv = make_float4(0.f, 0.f, 0.f, 0.f);
        float4 vv = make_float4(0.f, 0.f, 0.f, 0.f);
        if (krow < L) {
            int kvox = voxof(blk, krow, logs, lbsz);
            s16x4 k4 = *reinterpret_cast<const s16x4*>(QKV + (size_t)kvox * 768 + 256 + h * 32 + kd);
            s16x4 v4 = *reinterpret_cast<const s16x4*>(QKV + (size_t)kvox * 768 + 512 + h * 32 + kd);
            kv = make_float4(b2f((unsigned short)k4[0]), b2f((unsigned short)k4[1]),
                             b2f((unsigned short)k4[2]), b2f((unsigned short)k4[3]));
            vv = make_float4(b2f((unsigned short)v4[0]), b2f((unsigned short)v4[1]),
                             b2f((unsigned short)v4[2]), b2f((unsigned short)v4[3]));
        }
        __syncthreads();
        Kl3[krow][kd + 0] = kv.x; Kl3[krow][kd + 1] = kv.y;
        Kl3[krow][kd + 2] = kv.z; Kl3[krow][kd + 3] = kv.w;
        Vl3[krow][kd + 0] = vv.x; Vl3[krow][kd + 1] = vv.y;
        Vl3[krow][kd + 2] = vv.z; Vl3[krow][kd + 3] = vv.w;
        __syncthreads();
#pragma unroll
        for (int j = 0; j < 4; ++j) {
            int kk = j * 8 + li;
            float acc = 0.f;
#pragma unroll
            for (int d4 = 0; d4 < 8; ++d4) {
                float4 k4 = *reinterpret_cast<const float4*>(&Kl3[kk][d4 * 4]);
                acc += q[d4 * 4 + 0] * k4.x + q[d4 * 4 + 1] * k4.y +
                       q[d4 * 4 + 2] * k4.z + q[d4 * 4 + 3] * k4.w;
            }
            float p = (kk < L) ? exp2f(acc) : 0.f;
            l += p;
#pragma unroll
            for (int d4 = 0; d4 < 8; ++d4) {
                float4 v4 = *reinterpret_cast<const float4*>(&Vl3[kk][d4 * 4]);
                o[d4 * 4 + 0] += p * v4.x; o[d4 * 4 + 1] += p * v4.y;
                o[d4 * 4 + 2] += p * v4.z; o[d4 * 4 + 3] += p * v4.w;
            }
        }
#pragma unroll
        for (int d = 0; d < 32; ++d) {
            o[d] += __shfl_xor(o[d], 1);
            o[d] += __shfl_xor(o[d], 2);
            o[d] += __shfl_xor(o[d], 4);
        }
        l += __shfl_xor(l, 1);
        l += __shfl_xor(l, 2);
        l += __shfl_xor(l, 4);
        if (qr < L) {
            float inv = 1.0f / l;
            size_t orow = (size_t)qvox * 256 + h * 32;
#pragma unroll
            for (int qd = 0; qd < 4; ++qd) O[orow + li * 4 + qd] = f2b(o[li * 4 + qd] * inv);
        }
    }
}

// ---------------------------------------------------------------------------
// Fused inter attention: bid<512 = z3-inter MFMA (8 xb x 8 ks x 8 h, KS=8);
// bid in [512,560) = f32 inter z in {0,1,2} (L={1,8,64}), identity map.
// ---------------------------------------------------------------------------
__global__ __launch_bounds__(256) void attn_dfuse_k(
    const unsigned short* __restrict__ RQKVa, const unsigned short* __restrict__ Vtgr,
    unsigned short* __restrict__ OpartR, float* __restrict__ MLbuf,
    unsigned short* __restrict__ RObA) {
    int bid = blockIdx.x;
    const int tid = threadIdx.x;
    if (bid < 512) {
        __shared__ unsigned short Kl[2048];
        __shared__ unsigned short Vl[2048];
        __shared__ unsigned short Pl[4096];
        int xb = bid & 7, ks = (bid >> 3) & 7, h = bid >> 6;
        const int wave = tid >> 6;
        attn_core<0>(RQKVa + (size_t)73 * 768, Vtgr, OpartR, MLbuf,
                     512, 512, 0, 4, 0, h, 8, ks, xb * 64 + wave * 16, Kl, Vl, Pl);
    } else {
        __shared__ float Kl3[32][36];
        __shared__ float Vl3[32][36];
        int idx = bid - 512;                 // [0,48)
        const int bx = idx & 1, y = idx >> 1;
        const int z = y >> 3, h = y & 7;
        const int Lz[3] = {1, 8, 64};
        const int goffc3[3] = {0, 1, 9};
        const int L = Lz[z];
        const unsigned short* base = RQKVa + (size_t)goffc3[z] * 768;
        unsigned short* O = RObA + (size_t)goffc3[z] * 256;
        const int r = tid >> 3, li = tid & 7;
        const int qr = bx * 32 + r;
        const int qrc = (qr < L) ? qr : 0;
        float q[32];
        {
            const unsigned short* qp = base + (size_t)qrc * 768 + h * 32;
#pragma unroll
            for (int d8 = 0; d8 < 4; ++d8) {
                s16x8 v = *reinterpret_cast<const s16x8*>(qp + d8 * 8);
#pragma unroll
                for (int e = 0; e < 8; ++e) q[d8 * 8 + e] = b2f((unsigned short)v[e]);
            }
        }
        float l = 0.f;
        float o[32];
#pragma unroll
        for (int d = 0; d < 32; ++d) o[d] = 0.f;
        const int krow = tid >> 3, kd = (tid & 7) * 4;
        const int nt = (L + 31) / 32;
        for (int kt = 0; kt < nt; ++kt) {
            int key = kt * 32 + krow;
            float4 kv = make_float4(0.f, 0.f, 0.f, 0.f);
            float4 vv = make_float4(0.f, 0.f, 0.f, 0.f);
            if (key < L) {
                s16x4 k4 = *reinterpret_cast<const s16x4*>(base + (size_t)key * 768 + 256 + h * 32 + kd);
                s16x4 v4 = *reinterpret_cast<const s16x4*>(base + (size_t)key * 768 + 512 + h * 32 + kd);
                kv = make_float4(b2f((unsigned short)k4[0]), b2f((unsigned short)k4[1]),
                                 b2f((unsigned short)k4[2]), b2f((unsigned short)k4[3]));
                vv = make_float4(b2f((unsigned short)v4[0]), b2f((unsigned short)v4[1]),
                                 b2f((unsigned short)v4[2]), b2f((unsigned short)v4[3]));
            }
            __syncthreads();
            Kl3[krow][kd + 0] = kv.x; Kl3[krow][kd + 1] = kv.y;
            Kl3[krow][kd + 2] = kv.z; Kl3[krow][kd + 3] = kv.w;
            Vl3[krow][kd + 0] = vv.x; Vl3[krow][kd + 1] = vv.y;
            Vl3[krow][kd + 2] = vv.z; Vl3[krow][kd + 3] = vv.w;
            __syncthreads();
#pragma unroll
            for (int j = 0; j < 4; ++j) {
                int kk = j * 8 + li;
                float acc = 0.f;
#pragma unroll
                for (int d4 = 0; d4 < 8; ++d4) {
                    float4 k4 = *reinterpret_cast<const float4*>(&Kl3[kk][d4 * 4]);
                    acc += q[d4 * 4 + 0] * k4.x + q[d4 * 4 + 1] * k4.y +
                           q[d4 * 4 + 2] * k4.z + q[d4 * 4 + 3] * k4.w;
                }
                float p = (kt * 32 + kk < L) ? exp2f(acc) : 0.f;
                l += p;
#pragma unroll
                for (int d4 = 0; d4 < 8; ++d4) {
                    float4 v4 = *reinterpret_cast<const float4*>(&Vl3[kk][d4 * 4]);
                    o[d4 * 4 + 0] += p * v4.x; o[d4 * 4 + 1] += p * v4.y;
                    o[d4 * 4 + 2] += p * v4.z; o[d4 * 4 + 3] += p * v4.w;
                }
            }
        }
#pragma unroll
        for (int d = 0; d < 32; ++d) {
            o[d] += __shfl_xor(o[d], 1);
            o[d] += __shfl_xor(o[d], 2);
            o[d] += __shfl_xor(o[d], 4);
        }
        l += __shfl_xor(l, 1);
        l += __shfl_xor(l, 2);
        l += __shfl_xor(l, 4);
        if (qr < L) {
            float inv = 1.0f / l;
            size_t orow = (size_t)qr * 256 + h * 32;
#pragma unroll
            for (int qd = 0; qd < 4; ++qd) O[orow + li * 4 + qd] = f2b(o[li * 4 + qd] * inv);
        }
    }
}

// combine: O = sum_ks l*o_norm / sum_ks l  (inter, KS=8)
__global__ __launch_bounds__(256) void attn_combine_k(
    const unsigned short* __restrict__ Opart, const float* __restrict__ ML,
    unsigned short* __restrict__ O, int TotTok, int KS,
    long zOp, long zML, long zO) {
    int z = blockIdx.y, row = blockIdx.x, c = threadIdx.x, h = c >> 5;
    Opart += (size_t)z * zOp;
    ML += (size_t)z * zML;
    O += (size_t)z * zO;
    float osum = 0.f, lsum = 0.f;
    for (int ks = 0; ks < KS; ++ks) {
        float l = ML[((size_t)ks * TotTok + row) * 8 + h];
        lsum += l;
        osum += l * b2f(Opart[((size_t)ks * TotTok + row) * 256 + c]);
    }
    O[(size_t)row * 256 + c] = f2b(osum / lsum);
}

// ---------------------------------------------------------------------------
// intra residual+LN, batched: grid 4*4096; T1 bf16 in, T bf16 out
// ---------------------------------------------------------------------------
__global__ __launch_bounds__(256) void add_ln_b_k(const float* __restrict__ X,
                                                  const unsigned short* __restrict__ T1b,
                                                  const float* __restrict__ g,
                                                  const float* __restrict__ b,
                                                  unsigned short* __restrict__ Tb) {
    int row = blockIdx.x & 4095, z = blockIdx.x >> 12, t = threadIdx.x;
    float v = X[row * 256 + t] + b2f(T1b[(size_t)z * 1048576 + row * 256 + t]);
    float s1 = v, s2 = v * v;
#pragma unroll
    for (int mask = 1; mask < 64; mask <<= 1) {
        s1 += __shfl_xor(s1, mask);
        s2 += __shfl_xor(s2, mask);
    }
    __shared__ float w1[4], w2[4];
    int wv = t >> 6, ln = t & 63;
    if (ln == 0) { w1[wv] = s1; w2[wv] = s2; }
    __syncthreads();
    float tot1 = w1[0] + w1[1] + w1[2] + w1[3];
    float tot2 = w2[0] + w2[1] + w2[2] + w2[3];
    float mean = tot1 * (1.0f / 256.0f);
    float var = tot2 * (1.0f / 256.0f) - mean * mean;
    float rstd = rsqrtf(var + 1e-5f);
    Tb[(size_t)z * 1048576 + row * 256 + t] =
        f2b((v - mean) * rstd * g[z * 256 + t] + b[z * 256 + t]);
}

// batched inter residual+LN over all 585 rows
__global__ __launch_bounds__(256) void add_ln_i_k(const float* __restrict__ Rb_all,
                                                  const float* __restrict__ R1_all,
                                                  const float* __restrict__ g,
                                                  const float* __restrict__ b,
                                                  float* __restrict__ RLN_all) {
    int row = blockIdx.x, t = threadIdx.x;
    int z = (row == 0) ? 0 : (row < 9 ? 1 : (row < 73 ? 2 : 3));
    float v = Rb_all[row * 256 + t] + R1_all[row * 256 + t];
    float s1 = v, s2 = v * v;
#pragma unroll
    for (int mask = 1; mask < 64; mask <<= 1) {
        s1 += __shfl_xor(s1, mask);
        s2 += __shfl_xor(s2, mask);
    }
    __shared__ float w1[4], w2[4];
    int wv = t >> 6, ln = t & 63;
    if (ln == 0) { w1[wv] = s1; w2[wv] = s2; }
    __syncthreads();
    float tot1 = w1[0] + w1[1] + w1[2] + w1[3];
    float tot2 = w2[0] + w2[1] + w2[2] + w2[3];
    float mean = tot1 * (1.0f / 256.0f);
    float var = tot2 * (1.0f / 256.0f) - mean * mean;
    float rstd = rsqrtf(var + 1e-5f);
    RLN_all[row * 256 + t] = (v - mean) * rstd * g[z * 256 + t] + b[z * 256 + t];
}

// batched block means from bf16 T, bounded contention; grid 896
__global__ __launch_bounds__(256) void block_mean_b_k(const unsigned short* __restrict__ Tb_all,
                                                      float* __restrict__ Rb_all) {
    int bx = blockIdx.x, c = threadIdx.x;
    int z, blk, ch, rpc;
    float inv_bs;
    if (bx < 128)      { z = 0; blk = 0;               ch = bx;              rpc = 32; inv_bs = 1.0f / 4096.0f; }
    else if (bx < 256) { int l = bx - 128; z = 1; blk = l >> 4; ch = l & 15; rpc = 32; inv_bs = 1.0f / 512.0f; }
    else if (bx < 384) { int l = bx - 256; z = 2; blk = l >> 1; ch = l & 1;  rpc = 32; inv_bs = 1.0f / 64.0f; }
    else               { int l = bx - 384; z = 3; blk = l;      ch = 0;      rpc = 8;  inv_bs = 1.0f / 8.0f; }
    const int goffc[4] = {0, 1, 9, 73};
    const int logs = z, lbsz = 4 - z;
    const unsigned short* T = Tb_all + (size_t)z * 1048576;
    float* R = Rb_all + (size_t)(goffc[z] + blk) * 256;
    int p0 = ch * rpc;
    float sum = 0.f;
    for (int p = p0; p < p0 + rpc; ++p)
        sum += b2f(T[(size_t)voxof(blk, p, logs, lbsz) * 256 + c]);
    atomicAdd(&R[c], sum * inv_bs);
}

// BN stats over Yt [4096 vox][256 ch]
__global__ __launch_bounds__(256) void bn_stats_k(const float* __restrict__ Yt,
                                                  float* __restrict__ MV) {
    int b0 = blockIdx.x * 16, c = threadIdx.x;
    float s1 = 0.f, s2 = 0.f;
#pragma unroll
    for (int j = 0; j < 16; ++j) {
        float v = Yt[(size_t)(b0 + j) * 256 + c];
        s1 += v; s2 += v * v;
    }
    atomicAdd(&MV[c], s1);
    atomicAdd(&MV[256 + c], s2);
}

__global__ __launch_bounds__(256) void bn_apply_k(const float* __restrict__ Yt,
                                                  const float* __restrict__ MV,
                                                  const float* __restrict__ g,
                                                  const float* __restrict__ b,
                                                  float* __restrict__ outp) {
    int c = blockIdx.x, t = threadIdx.x;
    float mean = MV[c] * (1.0f / 4096.0f);
    float var = MV[256 + c] * (1.0f / 4096.0f) - mean * mean;
    float rstd = rsqrtf(var + 1e-5f);
    float gg = g[c] * rstd, bb = b[c] - mean * gg;
    for (int it = 0; it < 16; ++it) {
        int v = it * 256 + t;
        float y = Yt[(size_t)v * 256 + c];
        float rr = y * gg + bb;
        outp[(size_t)c * 4096 + v] = rr > 0.f ? rr : 0.f;
    }
}

// ---------------------------------------------------------------------------
extern "C" void kernel_launch(void* const* d_in, const int* in_sizes, int n_in,
                              void* d_out, int out_size, void* d_ws, size_t ws_size,
                              hipStream_t stream) {
    (void)in_sizes; (void)n_in; (void)out_size; (void)ws_size;
    const float* x          = (const float*)d_in[0];
    const float* intra_bqkv = (const float*)d_in[2];
    const float* intra_bout = (const float*)d_in[4];
    const float* intra_ln_g = (const float*)d_in[5];
    const float* intra_ln_b = (const float*)d_in[6];
    const float* inter_bqkv = (const float*)d_in[8];
    const float* inter_bout = (const float*)d_in[10];
    const float* inter_ln_g = (const float*)d_in[11];
    const float* inter_ln_b = (const float*)d_in[12];
    const float* ffn_b1     = (const float*)d_in[14];
    const float* ffn_b2     = (const float*)d_in[16];
    const float* bn_g       = (const float*)d_in[18];
    const float* bn_b       = (const float*)d_in[19];
    float* out = (float*)d_out;

    float* ws = (float*)d_ws;
    unsigned short* OUTt  = (unsigned short*)ws;                  // 2,097,152 f
    float* Xt             = ws + 2097152;                         // 1,048,576
    unsigned short* Xtb   = (unsigned short*)(ws + 3145728);      // 524,288
    unsigned short* QKVA2 = (unsigned short*)(ws + 3670016);      // [2][4096][768]
    unsigned short* ObfA  = (unsigned short*)(ws + 6815744);      // [4][4096][256]
    unsigned short* T1A   = (unsigned short*)(ws + 8912896);      // [4][4096][256] bf16
    unsigned short* TAb   = (unsigned short*)(ws + 11010048);     // [4][4096][256] bf16
    float* Rb_all         = ws + 13107200;                        // 149,760
    unsigned short* RQKVa = (unsigned short*)(ws + 13256960);     // 449,280 sh
    unsigned short* RObA  = (unsigned short*)(ws + 13481600);     // 149,760 sh
    float* R1A            = ws + 13556480;                        // 149,760
    float* RLN_all        = ws + 13706240;                        // 149,760
    unsigned short* WB    = (unsigned short*)(ws + 13856000);     // 3,407,872 sh
    unsigned short* VtgA  = (unsigned short*)(ws + 15559936);     // [2][256][4096]
    unsigned short* Vtgr  = (unsigned short*)(ws + 16608512);     // 131,072 sh
    float* MLbuf          = ws + 16674048;                        // 262,144 f
    // lifetime aliases:
    unsigned short* OpartI = T1A;                 // [2][4][4096][256] bf16 over T1A+TAb
    unsigned short* OpartR = T1A;                 // [8][512][256] bf16 (Phase D)
    unsigned short* HidA   = QKVA2;               // [4][4096][512] bf16 over QKVA2+ObfA
    float* MV              = MLbuf;               // 512 f32 (after attn)
    float* Yt              = Xt;                  // fuse output

    unsigned short* WBq  = WB;
    unsigned short* WBo  = WB + 786432;
    unsigned short* WBiq = WB + 1048576;
    unsigned short* WBio = WB + 1835008;
    unsigned short* WBf1 = WB + 2097152;
    unsigned short* WBf2 = WB + 2621440;
    unsigned short* WBfu = WB + 3145728;

    const long ZC = 1048576;

    prologue_k<<<4499, 256, 0, stream>>>((const float*)d_in[1], (const float*)d_in[3],
                                         (const float*)d_in[7], (const float*)d_in[9],
                                         (const float*)d_in[13], (const float*)d_in[15],
                                         (const float*)d_in[17], WB, x, Xt, Xtb, Rb_all);

    // ---- Phase A: QKV z in {0,1} (batched, V^T, Q pre-scaled) + fused MFMA attn ----
    gemm_k<4, 1, 0, 1, 1, 0, 0, 0, 1><<<dim3(12, 32, 2), 256, 0, stream>>>(
        Xtb, WBq, intra_bqkv, QKVA2, 4096, 768, 256, 768,
        0, 196608, 768, 3145728, VtgA, 4096, 1048576, TAb, Rb_all, Xt);
    attn_fused01_k<<<4096, 256, 0, stream>>>(QKVA2, VtgA, OpartI, MLbuf);
    // ---- QKV z in {2,3} (batched, V^T, Q pre-scaled) ----
    gemm_k<4, 1, 0, 1, 1, 0, 0, 0, 1><<<dim3(12, 32, 2), 256, 0, stream>>>(
        Xtb, WBq + 2 * 196608, intra_bqkv + 2 * 768, QKVA2, 4096, 768, 256, 768,
        0, 196608, 768, 3145728, VtgA, 4096, 1048576, TAb, Rb_all, Xt);
    // ---- Fused tail: combine01 + z2 MFMA (VST=1) + z3 f32 ----
    attn_tail_k<<<12800, 256, 0, stream>>>(OpartI, MLbuf, ObfA, QKVA2, VtgA, R1A);
    // ---- Phase B: batched out-projection -> T1A (bf16), MFR=2 ----
    gemm_k<2, 1, 0, 1, 0, 0, 0, 0, 0><<<dim3(4, 64, 4), 256, 0, stream>>>(
        ObfA, WBo, intra_bout, T1A, 4096, 256, 256, 256,
        ZC, 65536, 256, ZC, nullptr, 0, 0, TAb, Rb_all, Xt);
    // ---- Phase C: batched residual+LN -> TAb; block means -> Rb_all ----
    add_ln_b_k<<<16384, 256, 0, stream>>>(Xt, T1A, intra_ln_g, intra_ln_b, TAb);
    block_mean_b_k<<<896, 256, 0, stream>>>(TAb, Rb_all);
    // ---- Phase D: inter chain (Q pre-scaled in D1) ----
    gemm_k<2, 1, 0, 1, 1, 1, 0, 2, 1><<<dim3(12, 8, 4), 256, 0, stream>>>(
        Rb_all, WBiq, inter_bqkv, RQKVa, 512, 768, 256, 768,
        0, 196608, 768, 0, Vtgr, 512, 0, TAb, Rb_all, Xt);
    attn_dfuse_k<<<560, 256, 0, stream>>>(RQKVa, Vtgr, OpartR, MLbuf, RObA);
    attn_combine_k<<<dim3(512, 1), 256, 0, stream>>>(
        OpartR, MLbuf, RObA + (size_t)73 * 256, 512, 8, 0, 0, 0);
    gemm_k<2, 1, 0, 0, 0, 0, 0, 2, 0><<<dim3(4, 8, 4), 256, 0, stream>>>(
        RObA, WBio, inter_bout, R1A, 512, 256, 256, 256,
        0, 65536, 256, 0, nullptr, 0, 0, TAb, Rb_all, Xt);
    add_ln_i_k<<<585, 256, 0, stream>>>(Rb_all, R1A, inter_ln_g, inter_ln_b, RLN_all);
    // ---- Phase E: batched FFN1 (bf16 T + RLN fused A, GELU) -> HidA ----
    gemm_k<4, 1, 1, 1, 0, 3, 0, 1, 0><<<dim3(8, 32, 4), 256, 0, stream>>>(
        TAb, WBf1, ffn_b1, HidA, 4096, 512, 256, 512,
        ZC, 131072, 512, 2097152, nullptr, 0, 0, TAb, RLN_all, Xt);
    // ---- Phase F: batched FFN2 (+T+RLN+X residuals) -> OUTt columns, MFR=2 ----
    gemm_k<2, 1, 0, 1, 0, 0, 1, 1, 0><<<dim3(4, 64, 4), 256, 0, stream>>>(
        HidA, WBf2, ffn_b2, OUTt, 4096, 256, 512, 1024,
        2097152, 131072, 256, 256, nullptr, 0, 0, TAb, RLN_all, Xt);
    // ---- Phase G: fuse conv + BN + ReLU, MFR=2 ----
    gemm_k<2, 0, 0, 0, 0, 0, 0, 0, 0><<<dim3(4, 64, 1), 256, 0, stream>>>(
        OUTt, WBfu, nullptr, Yt, 4096, 256, 1024, 256,
        0, 0, 0, 0, nullptr, 0, 0, TAb, Rb_all, Xt);
    hipMemsetAsync(MV, 0, 512 * sizeof(float), stream);
    bn_stats_k<<<256, 256, 0, stream>>>(Yt, MV);
    bn_apply_k<<<256, 256, 0, stream>>>(Yt, MV, bn_g, bn_b, out);
}